// Round 9
// baseline (97656.360 us; speedup 1.0000x reference)
//
#include <hip/hip_runtime.h>

#define NMOL 256
#define MOLS 48
#define NATOMS 12288           // NMOL*MOLS
#define NORB 192               // 4*MOLS
#define PPM 1128               // pairs per molecule = 48*47/2
#define NPAIR 288768           // NMOL*PPM
#define MATSZ 36864            // NORB*NORB
#define EVC 27.21f

// output offsets (floats)
#define F_OFF   0
#define E_OFF   9437184
#define P_OFF   9486336
#define H_OFF   18923520
#define WMAT_OFF 28360704
#define CHG_OFF 57237504
#define NCV_OFF 57249792

__device__ __forceinline__ int pairoff(int i, int j) {
    return 47 * i - (i * (i - 1)) / 2 + (j - i - 1);
}

// ---------------- per-pair: w_ss + Hcore off-diagonal blocks ----------------
__global__ void pair_kernel(
    const int* __restrict__ idxi, const int* __restrict__ idxj,
    const float* __restrict__ xij, const float* __restrict__ rij,
    const float* __restrict__ zeta_s, const float* __restrict__ zeta_p,
    const float* __restrict__ g_ss,
    const float* __restrict__ beta_s, const float* __restrict__ beta_p,
    float* __restrict__ wss, float* __restrict__ H)
{
    int pp = blockIdx.x * blockDim.x + threadIdx.x;
    if (pp >= NPAIR) return;
    int i = idxi[pp], j = idxj[pp];
    float r = rij[pp];
    float rho = 7.0f / g_ss[i] + 7.0f / g_ss[j];
    float base = 1.0f / sqrtf(r * r + rho * rho);
    float wv = EVC * base;
    wss[pp] = wv;

    float x[3] = { xij[pp * 3 + 0], xij[pp * 3 + 1], xij[pp * 3 + 2] };
    float zsi = zeta_s[i], zpi = zeta_p[i], zsj = zeta_s[j], zpj = zeta_p[j];
    float e_ss = expf(-0.5f * (zsi + zsj) * r);
    float e_sp = expf(-0.5f * (zsi + zpj) * r);
    float e_ps = expf(-0.5f * (zpi + zsj) * r);
    float e_pp = expf(-0.5f * (zpi + zpj) * r);

    float S[4][4];
    S[0][0] = e_ss;
    #pragma unroll
    for (int k = 0; k < 3; ++k) {
        S[0][1 + k] = x[k] * e_sp;
        S[1 + k][0] = -x[k] * e_ps;
        #pragma unroll
        for (int l = 0; l < 3; ++l)
            S[1 + k][1 + l] = ((k == l ? 1.0f : 0.0f) - x[k] * x[l]) * e_pp;
    }
    float boi[4] = { beta_s[i], beta_p[i], beta_p[i], beta_p[i] };
    float boj[4] = { beta_s[j], beta_p[j], beta_p[j], beta_p[j] };

    int mol = i / MOLS, ai = i % MOLS, aj = j % MOLS;
    float* Hm = H + (size_t)mol * MATSZ;
    #pragma unroll
    for (int p = 0; p < 4; ++p)
        #pragma unroll
        for (int q = 0; q < 4; ++q) {
            float v = 0.5f * (boi[p] + boj[q]) * S[p][q];
            Hm[(4 * ai + p) * NORB + 4 * aj + q] = v;
            Hm[(4 * aj + q) * NORB + 4 * ai + p] = v;
        }
}

// ---------------- w output (coalesced) ----------------
__global__ void wout_kernel(const float* __restrict__ wss, float* __restrict__ w_out)
{
    int idx = blockIdx.x * blockDim.x + threadIdx.x;
    if (idx >= NPAIR * 100) return;
    int pp = idx / 100, ab = idx % 100;
    int a = ab / 10, b = ab % 10;
    w_out[idx] = wss[pp] * (1.0f + 0.05f * (float)a) * (1.0f + 0.05f * (float)b);
}

// ---------------- per-atom: vatt gather + Hcore diagonal blocks ----------------
__global__ void atom_kernel(const int* __restrict__ Z,
    const float* __restrict__ U_ss, const float* __restrict__ U_pp,
    const float* __restrict__ wss, float* __restrict__ H)
{
    int a = blockIdx.x * blockDim.x + threadIdx.x;
    if (a >= NATOMS) return;
    int mol = a / MOLS, ai = a % MOLS;
    const float* wm = wss + mol * PPM;
    float vatt = 0.0f;
    for (int j = 0; j < MOLS; ++j) {
        if (j == ai) continue;
        int i_ = ai < j ? ai : j;
        int j_ = ai < j ? j : ai;
        float torej = (float)(Z[mol * MOLS + j] - 2);
        vatt -= torej * wm[pairoff(i_, j_)];
    }
    float u0 = U_ss[a], u1 = U_pp[a];
    float* Hm = H + (size_t)mol * MATSZ;
    #pragma unroll
    for (int p = 0; p < 4; ++p)
        #pragma unroll
        for (int q = 0; q < 4; ++q)
            Hm[(4 * ai + p) * NORB + 4 * ai + q] =
                (p == q) ? ((p == 0 ? u0 : u1) + vatt) : 0.0f;
}

// ---------------- initial density ----------------
__global__ void pinit_kernel(const int* __restrict__ Z, float* __restrict__ P)
{
    int idx = blockIdx.x * blockDim.x + threadIdx.x;
    if (idx >= NMOL * MATSZ) return;
    int mol = idx / MATSZ, rem = idx % MATSZ;
    int r = rem / NORB, c = rem % NORB;
    float v = 0.0f;
    if (r == c) v = (float)(Z[mol * MOLS + r / 4] - 2) * 0.25f;
    P[idx] = v;
}

// ---------------- Ptot (trace of diagonal density block) ----------------
__global__ void ptot_kernel(const float* __restrict__ P, float* __restrict__ Ptot)
{
    int a = blockIdx.x * blockDim.x + threadIdx.x;
    if (a >= NATOMS) return;
    int mol = a / MOLS, ai = a % MOLS;
    const float* Pm = P + (size_t)mol * MATSZ;
    float t = 0.0f;
    #pragma unroll
    for (int p = 0; p < 4; ++p) t += Pm[(4 * ai + p) * NORB + 4 * ai + p];
    Ptot[a] = t;
}

// ---------------- Fock diagonal blocks ----------------
__global__ void fockdiag_kernel(
    const float* __restrict__ P, const float* __restrict__ H, float* __restrict__ F,
    const float* __restrict__ Ptot, const float* __restrict__ wss,
    const float* __restrict__ g_ss, const float* __restrict__ g_sp,
    const float* __restrict__ g_pp, const float* __restrict__ g_p2,
    const float* __restrict__ h_sp)
{
    int a = blockIdx.x * blockDim.x + threadIdx.x;
    if (a >= NATOMS) return;
    int mol = a / MOLS, ai = a % MOLS;
    const float* wm = wss + mol * PPM;
    const float* ptm = Ptot + mol * MOLS;
    float vc = 0.0f;
    for (int j = 0; j < MOLS; ++j) {
        if (j == ai) continue;
        int i_ = ai < j ? ai : j;
        int j_ = ai < j ? j : ai;
        vc += wm[pairoff(i_, j_)] * ptm[j];
    }
    const float* Pm = P + (size_t)mol * MATSZ;
    float Pd[4][4];
    #pragma unroll
    for (int p = 0; p < 4; ++p)
        #pragma unroll
        for (int q = 0; q < 4; ++q)
            Pd[p][q] = Pm[(4 * ai + p) * NORB + 4 * ai + q];

    float Pss = Pd[0][0];
    float Pp0 = Pd[1][1], Pp1 = Pd[2][2], Pp2 = Pd[3][3];
    float Ppp = Pp0 + Pp1 + Pp2;
    float gss = g_ss[a], gsp = g_sp[a], gpp = g_pp[a], gp2 = g_p2[a], hsp = h_sp[a];
    float csp = 1.5f * hsp - 0.5f * gsp;
    float gsp_h = gsp - 0.5f * hsp;
    float fss = 0.5f * Pss * gss + Ppp * gsp_h;
    float cp = 1.25f * gp2 - 0.25f * gpp;
    float fpp0 = Pss * gsp_h + 0.5f * Pp0 * gpp + (Ppp - Pp0) * cp;
    float fpp1 = Pss * gsp_h + 0.5f * Pp1 * gpp + (Ppp - Pp1) * cp;
    float fpp2 = Pss * gsp_h + 0.5f * Pp2 * gpp + (Ppp - Pp2) * cp;
    float coff = 0.75f * gpp - 1.25f * gp2;

    float Fd[4][4];
    Fd[0][0] = fss + vc;
    Fd[1][1] = fpp0 + vc; Fd[2][2] = fpp1 + vc; Fd[3][3] = fpp2 + vc;
    #pragma unroll
    for (int k = 0; k < 3; ++k) {
        Fd[0][1 + k] = Pd[0][1 + k] * csp;
        Fd[1 + k][0] = Pd[1 + k][0] * csp;
    }
    Fd[1][2] = coff * Pd[1][2]; Fd[1][3] = coff * Pd[1][3];
    Fd[2][1] = coff * Pd[2][1]; Fd[2][3] = coff * Pd[2][3];
    Fd[3][1] = coff * Pd[3][1]; Fd[3][2] = coff * Pd[3][2];

    const float* Hm = H + (size_t)mol * MATSZ;
    float* Fm = F + (size_t)mol * MATSZ;
    #pragma unroll
    for (int p = 0; p < 4; ++p)
        #pragma unroll
        for (int q = 0; q < 4; ++q) {
            int ix = (4 * ai + p) * NORB + 4 * ai + q;
            Fm[ix] = Hm[ix] + Fd[p][q];
        }
}

// ---------------- Fock off-diagonal blocks ----------------
__global__ void fockoff_kernel(const int* __restrict__ idxi, const int* __restrict__ idxj,
    const float* __restrict__ P, const float* __restrict__ H, float* __restrict__ F,
    const float* __restrict__ wss)
{
    int pp = blockIdx.x * blockDim.x + threadIdx.x;
    if (pp >= NPAIR) return;
    int i = idxi[pp], j = idxj[pp];
    int mol = i / MOLS, ai = i % MOLS, aj = j % MOLS;
    float wv = wss[pp];
    const float* Pm = P + (size_t)mol * MATSZ;
    const float* Hm = H + (size_t)mol * MATSZ;
    float* Fm = F + (size_t)mol * MATSZ;
    #pragma unroll
    for (int p = 0; p < 4; ++p)
        #pragma unroll
        for (int q = 0; q < 4; ++q) {
            int ij = (4 * ai + p) * NORB + 4 * aj + q;
            int ji = (4 * aj + q) * NORB + 4 * ai + p;
            float f = -0.5f * wv * Pm[ij];
            Fm[ij] = Hm[ij] + f;
            Fm[ji] = Hm[ji] + f;
        }
}

// ---------------- batched eigensolver: one-sided Jacobi on sigma*I - F ----------------
// G=8 super-players: 24 players x 8 cols; 12 matches x 64 lanes (768 threads, 12 waves).
// Sweep = 23 cross rounds (64 pairs/match in 8 wave-internal phases) + 1 intra round
// (28 pairs/player, 7 phases) = 24 barriers (vs 48 at G=4, 96 at G=2, 191 scalar).
// Cols loaded per pair = 0.25 (vs 0.5 at G=4). Per lane: 3 floats per column.
// Occupancy 12 waves/CU (vs 6) doubles latency hiding. Same rotation math /
// incremental norms / tol2 write-skip / warm-start matvec as R6-R8.
#define EIG_T 768
#define ESTR 196     // padded column stride in floats
#define ESTR4 49     // in float4
#define EIG_LDS (( (ESTR*NORB) + 2*NORB ) * 4 + NORB * 4)

__device__ __forceinline__ float rsum64(float v) {
    v += __shfl_xor(v, 1); v += __shfl_xor(v, 2); v += __shfl_xor(v, 4);
    v += __shfl_xor(v, 8); v += __shfl_xor(v, 16); v += __shfl_xor(v, 32);
    return v;
}

// rotate pair (a,b) of 3-float slices if above threshold; exact incremental norms
__device__ __forceinline__ bool jrot3(float d, float& na, float& nb,
                                      float* a, float* b, float tol2) {
    if (d * d > tol2 * na * nb) {
        float zeta = (nb - na) / (2.0f * d);
        float t = copysignf(1.0f, zeta) / (fabsf(zeta) + sqrtf(1.0f + zeta * zeta));
        float cc = 1.0f / sqrtf(1.0f + t * t), ss = t * cc;
        #pragma unroll
        for (int u = 0; u < 3; ++u) {
            float av = a[u], bv = b[u];
            a[u] = cc * av - ss * bv;
            b[u] = ss * av + cc * bv;
        }
        float del = t * d; na -= del; nb += del;
        return true;
    }
    return false;
}

__global__ void __launch_bounds__(EIG_T)
eigh_kernel(const float* __restrict__ Fg, const int* __restrict__ noccA,
            const float* __restrict__ Vin, float* __restrict__ Vout,
            float* __restrict__ Wout, float* __restrict__ eout,
            int mode, int warm, int nsweep)
{
    extern __shared__ float sm[];
    float* B = sm;                          // ESTR*NORB
    float* colv = sm + ESTR * NORB;         // NORB (norms^2, tracked)
    float* colv2 = colv + NORB;             // NORB
    int* slot = (int*)(colv2 + NORB);       // NORB
    __shared__ float sigma;

    const int mol = blockIdx.x;
    const int tid = threadIdx.x;
    const float* Fm = Fg + (size_t)mol * MATSZ;
    float4* B4 = (float4*)B;

    if (!warm) {
        // cold: load F into LDS (padded columns; symmetric so col-major == row-major)
        for (int i4 = tid; i4 < NORB * 48; i4 += EIG_T) {
            int c = i4 / 48, r4 = i4 % 48;
            B4[c * ESTR4 + r4] = ((const float4*)Fm)[i4];
        }
        __syncthreads();
        // Gershgorin per column from LDS (4 lanes per column)
        {
            int c = tid >> 2, part = tid & 3;
            const float4* col = (const float4*)B + c * ESTR4 + part * 12;
            float s = 0.0f;
            #pragma unroll
            for (int u = 0; u < 12; ++u) {
                float4 v = col[u];
                s += fabsf(v.x) + fabsf(v.y) + fabsf(v.z) + fabsf(v.w);
            }
            s += __shfl_xor(s, 1); s += __shfl_xor(s, 2);
            if (part == 0) { float d = B[c * ESTR + c]; colv[c] = s - fabsf(d) + d; }
        }
        __syncthreads();
        if (tid < 64) {
            float m = -3.4e38f;
            for (int i = tid; i < NORB; i += 64) m = fmaxf(m, colv[i]);
            #pragma unroll
            for (int o = 32; o >= 1; o >>= 1) m = fmaxf(m, __shfl_xor(m, o));
            if (tid == 0) sigma = m + 1.0f + 1e-3f * fabsf(m);
        }
        __syncthreads();
        float sg = sigma;
        // B = sigma*I - F
        for (int i4 = tid; i4 < NORB * 48; i4 += EIG_T) {
            int c = i4 / 48, r4 = i4 % 48;
            float4* pv = B4 + c * ESTR4 + r4;
            float4 v = *pv;
            v.x = -v.x; v.y = -v.y; v.z = -v.z; v.w = -v.w;
            *pv = v;
        }
        __syncthreads();
        if (tid < NORB) B[tid * ESTR + tid] += sg;
        __syncthreads();
    } else {
        // warm: load Vprev into LDS
        for (int i4 = tid; i4 < NORB * 48; i4 += EIG_T) {
            int c = i4 / 48, r4 = i4 % 48;
            B4[c * ESTR4 + r4] = ((const float4*)Vin)[(size_t)mol * (MATSZ / 4) + i4];
        }
        // Gershgorin per column from GLOBAL F (no dependency on V load)
        {
            int c = tid >> 2, part = tid & 3;
            const float4* col = (const float4*)(Fm + c * NORB) + part * 12;
            float s = 0.0f;
            #pragma unroll
            for (int u = 0; u < 12; ++u) {
                float4 v = col[u];
                s += fabsf(v.x) + fabsf(v.y) + fabsf(v.z) + fabsf(v.w);
            }
            s += __shfl_xor(s, 1); s += __shfl_xor(s, 2);
            if (part == 0) { float d = Fm[c * NORB + c]; colv[c] = s - fabsf(d) + d; }
        }
        __syncthreads();
        if (tid < 64) {
            float m = -3.4e38f;
            for (int i = tid; i < NORB; i += 64) m = fmaxf(m, colv[i]);
            #pragma unroll
            for (int o = 32; o >= 1; o >>= 1) m = fmaxf(m, __shfl_xor(m, o));
            if (tid == 0) sigma = m + 1.0f + 1e-3f * fabsf(m);
        }
        __syncthreads();
        float sg = sigma;
        // B[:,j] = sg*V[:,j] - F*V[:,j]; 96 teams of 8 lanes, 2 cols each, one pass.
        {
            int t8 = tid >> 3, l8 = tid & 7;
            int j0 = 2 * t8, j1 = j0 + 1;
            float4 acc0[6], acc1[6];
            #pragma unroll
            for (int u = 0; u < 6; ++u) {
                acc0[u].x = acc0[u].y = acc0[u].z = acc0[u].w = 0.0f;
                acc1[u].x = acc1[u].y = acc1[u].z = acc1[u].w = 0.0f;
            }
            const float4* F4 = (const float4*)Fm;
            for (int k = 0; k < NORB; ++k) {
                float v0 = B[j0 * ESTR + k];
                float v1 = B[j1 * ESTR + k];
                const float4* Fk = F4 + k * 48 + l8;
                #pragma unroll
                for (int u = 0; u < 6; ++u) {
                    float4 f = Fk[8 * u];
                    acc0[u].x += f.x * v0; acc0[u].y += f.y * v0;
                    acc0[u].z += f.z * v0; acc0[u].w += f.w * v0;
                    acc1[u].x += f.x * v1; acc1[u].y += f.y * v1;
                    acc1[u].z += f.z * v1; acc1[u].w += f.w * v1;
                }
            }
            #pragma unroll
            for (int u = 0; u < 6; ++u) {
                int r4 = l8 + 8 * u;
                float4* pa = B4 + j0 * ESTR4 + r4;
                float4* pb = B4 + j1 * ESTR4 + r4;
                float4 va = *pa, vb = *pb, oa, ob;
                oa.x = sg * va.x - acc0[u].x; oa.y = sg * va.y - acc0[u].y;
                oa.z = sg * va.z - acc0[u].z; oa.w = sg * va.w - acc0[u].w;
                ob.x = sg * vb.x - acc1[u].x; ob.y = sg * vb.y - acc1[u].y;
                ob.z = sg * vb.z - acc1[u].z; ob.w = sg * vb.w - acc1[u].w;
                *pa = oa; *pb = ob;
            }
        }
        __syncthreads();
    }
    float sg = sigma;

    // exact initial column norms^2 into colv (tracked incrementally during sweeps)
    {
        int c = tid >> 2, part = tid & 3;
        const float4* col = (const float4*)B + c * ESTR4 + part * 12;
        float s = 0.0f;
        #pragma unroll
        for (int u = 0; u < 12; ++u) {
            float4 v = col[u];
            s += v.x * v.x + v.y * v.y + v.z * v.z + v.w * v.w;
        }
        s += __shfl_xor(s, 1); s += __shfl_xor(s, 2);
        if (part == 0) colv[c] = s;
    }
    __syncthreads();

    const float tol2 = 2.5e-11f;   // (5e-6 rel)^2, validated numerics
    const int wv = tid >> 6, lane = tid & 63;   // 12 waves, 64 lanes

    for (int sweep = 0; sweep < nsweep; ++sweep) {
        // ---- 23 cross rounds over 24 players (8 cols each); team = one wave ----
        int p, q;
        if (wv == 0) { p = 23; q = 0; }
        else         { p = wv;  q = 23 - wv; }
        for (int r = 0; r < 23; ++r) {
            float xp[8][3], xq[8][3];
            float np[8], nq[8];
            bool wp[8] = {false,false,false,false,false,false,false,false};
            bool wq[8] = {false,false,false,false,false,false,false,false};
            #pragma unroll
            for (int i = 0; i < 8; ++i) {
                const float* ap = B + (8 * p + i) * ESTR + 3 * lane;
                const float* aq = B + (8 * q + i) * ESTR + 3 * lane;
                xp[i][0] = ap[0]; xp[i][1] = ap[1]; xp[i][2] = ap[2];
                xq[i][0] = aq[0]; xq[i][1] = aq[1]; xq[i][2] = aq[2];
                np[i] = colv[8 * p + i]; nq[i] = colv[8 * q + i];
            }
            // 8 wave-internal phases of 8 disjoint pairs (p_i, q_{(i+s)&7})
            #pragma unroll
            for (int s = 0; s < 8; ++s) {
                float d[8];
                #pragma unroll
                for (int i = 0; i < 8; ++i) {
                    const int j = (i + s) & 7;
                    d[i] = xp[i][0] * xq[j][0] + xp[i][1] * xq[j][1] + xp[i][2] * xq[j][2];
                }
                #pragma unroll
                for (int i = 0; i < 8; ++i) d[i] = rsum64(d[i]);
                #pragma unroll
                for (int i = 0; i < 8; ++i) {
                    const int j = (i + s) & 7;
                    if (jrot3(d[i], np[i], nq[j], xp[i], xq[j], tol2)) {
                        wp[i] = true; wq[j] = true;
                    }
                }
            }
            #pragma unroll
            for (int i = 0; i < 8; ++i) {
                if (wp[i]) {
                    float* ap = B + (8 * p + i) * ESTR + 3 * lane;
                    ap[0] = xp[i][0]; ap[1] = xp[i][1]; ap[2] = xp[i][2];
                }
                if (wq[i]) {
                    float* aq = B + (8 * q + i) * ESTR + 3 * lane;
                    aq[0] = xq[i][0]; aq[1] = xq[i][1]; aq[2] = xq[i][2];
                }
            }
            if (lane == 0) {
                #pragma unroll
                for (int i = 0; i < 8; ++i) {
                    colv[8 * p + i] = np[i]; colv[8 * q + i] = nq[i];
                }
            }
            __syncthreads();
            if (wv != 0) p = (p == 22) ? 0 : p + 1;
            q = (q == 22) ? 0 : q + 1;
        }

        // ---- intra-player round: wave w handles players 2w, 2w+1 (28 pairs each) ----
        {
            const int plA = 2 * wv, plB = plA + 1;
            float xa[8][3], xb[8][3];
            float na[8], nb[8];
            bool wa[8] = {false,false,false,false,false,false,false,false};
            bool wb[8] = {false,false,false,false,false,false,false,false};
            #pragma unroll
            for (int i = 0; i < 8; ++i) {
                const float* aa = B + (8 * plA + i) * ESTR + 3 * lane;
                const float* ab = B + (8 * plB + i) * ESTR + 3 * lane;
                xa[i][0] = aa[0]; xa[i][1] = aa[1]; xa[i][2] = aa[2];
                xb[i][0] = ab[0]; xb[i][1] = ab[1]; xb[i][2] = ab[2];
                na[i] = colv[8 * plA + i]; nb[i] = colv[8 * plB + i];
            }
            // circle method on 8 items: round r: (r,7), ((r+1)%7,(r+6)%7),
            // ((r+2)%7,(r+5)%7), ((r+3)%7,(r+4)%7) — 7 rounds x 4 disjoint pairs
            #pragma unroll
            for (int r7 = 0; r7 < 7; ++r7) {
                const int i0 = r7,            j0 = 7;
                const int i1 = (r7 + 1) % 7,  j1 = (r7 + 6) % 7;
                const int i2 = (r7 + 2) % 7,  j2 = (r7 + 5) % 7;
                const int i3 = (r7 + 3) % 7,  j3 = (r7 + 4) % 7;
                float d[8];
                d[0] = xa[i0][0]*xa[j0][0] + xa[i0][1]*xa[j0][1] + xa[i0][2]*xa[j0][2];
                d[1] = xa[i1][0]*xa[j1][0] + xa[i1][1]*xa[j1][1] + xa[i1][2]*xa[j1][2];
                d[2] = xa[i2][0]*xa[j2][0] + xa[i2][1]*xa[j2][1] + xa[i2][2]*xa[j2][2];
                d[3] = xa[i3][0]*xa[j3][0] + xa[i3][1]*xa[j3][1] + xa[i3][2]*xa[j3][2];
                d[4] = xb[i0][0]*xb[j0][0] + xb[i0][1]*xb[j0][1] + xb[i0][2]*xb[j0][2];
                d[5] = xb[i1][0]*xb[j1][0] + xb[i1][1]*xb[j1][1] + xb[i1][2]*xb[j1][2];
                d[6] = xb[i2][0]*xb[j2][0] + xb[i2][1]*xb[j2][1] + xb[i2][2]*xb[j2][2];
                d[7] = xb[i3][0]*xb[j3][0] + xb[i3][1]*xb[j3][1] + xb[i3][2]*xb[j3][2];
                #pragma unroll
                for (int i = 0; i < 8; ++i) d[i] = rsum64(d[i]);
                if (jrot3(d[0], na[i0], na[j0], xa[i0], xa[j0], tol2)) { wa[i0] = wa[j0] = true; }
                if (jrot3(d[1], na[i1], na[j1], xa[i1], xa[j1], tol2)) { wa[i1] = wa[j1] = true; }
                if (jrot3(d[2], na[i2], na[j2], xa[i2], xa[j2], tol2)) { wa[i2] = wa[j2] = true; }
                if (jrot3(d[3], na[i3], na[j3], xa[i3], xa[j3], tol2)) { wa[i3] = wa[j3] = true; }
                if (jrot3(d[4], nb[i0], nb[j0], xb[i0], xb[j0], tol2)) { wb[i0] = wb[j0] = true; }
                if (jrot3(d[5], nb[i1], nb[j1], xb[i1], xb[j1], tol2)) { wb[i1] = wb[j1] = true; }
                if (jrot3(d[6], nb[i2], nb[j2], xb[i2], xb[j2], tol2)) { wb[i2] = wb[j2] = true; }
                if (jrot3(d[7], nb[i3], nb[j3], xb[i3], xb[j3], tol2)) { wb[i3] = wb[j3] = true; }
            }
            #pragma unroll
            for (int i = 0; i < 8; ++i) {
                if (wa[i]) {
                    float* aa = B + (8 * plA + i) * ESTR + 3 * lane;
                    aa[0] = xa[i][0]; aa[1] = xa[i][1]; aa[2] = xa[i][2];
                }
                if (wb[i]) {
                    float* ab = B + (8 * plB + i) * ESTR + 3 * lane;
                    ab[0] = xb[i][0]; ab[1] = xb[i][1]; ab[2] = xb[i][2];
                }
            }
            if (lane == 0) {
                #pragma unroll
                for (int i = 0; i < 8; ++i) {
                    colv[8 * plA + i] = na[i]; colv[8 * plB + i] = nb[i];
                }
            }
            __syncthreads();
        }
    }

    // exact column norms^2
    {
        int c = tid >> 2, part = tid & 3;
        const float4* col = (const float4*)B + c * ESTR4 + part * 12;
        float s = 0.0f;
        #pragma unroll
        for (int u = 0; u < 12; ++u) {
            float4 v = col[u];
            s += v.x * v.x + v.y * v.y + v.z * v.z + v.w * v.w;
        }
        s += __shfl_xor(s, 1); s += __shfl_xor(s, 2);
        if (part == 0) colv[c] = s;
    }
    __syncthreads();

    if (mode == 0) {
        // occupied = nocc largest norms (= smallest eigenvalues of F)
        int noccm = noccA[mol];
        if (tid < NORB) {
            float nc = colv[tid];
            int rank = 0;
            for (int j2 = 0; j2 < NORB; ++j2) {
                float nj = colv[j2];
                rank += (nj > nc) || (nj == nc && j2 < tid);
            }
            slot[tid] = rank;
            colv2[tid] = rsqrtf(nc);     // 1/||b||
        }
        __syncthreads();
        float* Wm = Wout + (size_t)mol * MATSZ;
        float* Vm = Vout + (size_t)mol * MATSZ;
        for (int i4 = tid; i4 < NORB * 48; i4 += EIG_T) {
            int c = i4 / 48, r4 = i4 % 48;
            float inv = colv2[c];
            float4 v = B4[c * ESTR4 + r4];
            float4 nv;
            nv.x = v.x * inv; nv.y = v.y * inv; nv.z = v.z * inv; nv.w = v.w * inv;
            ((float4*)Vm)[i4] = nv;      // full basis for next warm start
            int sl = slot[c];
            if (sl < noccm) {
                float4 o;
                o.x = nv.x * 1.41421356f; o.y = nv.y * 1.41421356f;
                o.z = nv.z * 1.41421356f; o.w = nv.w * 1.41421356f;
                ((float4*)Wm)[sl * 48 + r4] = o;
            }
        }
    } else {
        // eigenvalues ascending
        if (tid < NORB) colv2[tid] = sg - sqrtf(colv[tid]);
        __syncthreads();
        if (tid < NORB) {
            float ec = colv2[tid];
            int rank = 0;
            for (int j2 = 0; j2 < NORB; ++j2) {
                float ej = colv2[j2];
                rank += (ej < ec) || (ej == ec && j2 < tid);
            }
            eout[mol * NORB + rank] = ec;
        }
    }
}

// ---------------- Pnew = W^T W, mix, err ----------------
__global__ void __launch_bounds__(256)
pmix_kernel(const float* __restrict__ W, const int* __restrict__ noccA,
            float* __restrict__ P, unsigned int* __restrict__ err, int last)
{
    int mol = blockIdx.x / 36;
    int tile = blockIdx.x % 36;
    int i0 = (tile / 6) * 32, j0 = (tile % 6) * 32;
    int K = noccA[mol];
    const float* Wm = W + (size_t)mol * MATSZ;
    __shared__ float As[32][33];
    __shared__ float Bs[32][33];
    int t = threadIdx.x;
    int ty = t >> 4, tx = t & 15;
    float acc00 = 0.f, acc01 = 0.f, acc10 = 0.f, acc11 = 0.f;
    for (int k0 = 0; k0 < K; k0 += 32) {
        for (int l = t; l < 1024; l += 256) {
            int k = l >> 5, idx = l & 31;
            bool ok = (k0 + k) < K;
            As[k][idx] = ok ? Wm[(k0 + k) * NORB + i0 + idx] : 0.0f;
            Bs[k][idx] = ok ? Wm[(k0 + k) * NORB + j0 + idx] : 0.0f;
        }
        __syncthreads();
        #pragma unroll 8
        for (int k = 0; k < 32; ++k) {
            float a0 = As[k][2 * ty], a1 = As[k][2 * ty + 1];
            float b0 = Bs[k][2 * tx], b1 = Bs[k][2 * tx + 1];
            acc00 += a0 * b0; acc01 += a0 * b1; acc10 += a1 * b0; acc11 += a1 * b1;
        }
        __syncthreads();
    }
    float* Pm = P + (size_t)mol * MATSZ;
    float lmax = 0.0f;
    int ib = i0 + 2 * ty, jb = j0 + 2 * tx;
    {
        float po, pn;
        po = Pm[ib * NORB + jb];           pn = acc00; lmax = fmaxf(lmax, fabsf(pn - po)); Pm[ib * NORB + jb] = 0.5f * (po + pn);
        po = Pm[ib * NORB + jb + 1];       pn = acc01; lmax = fmaxf(lmax, fabsf(pn - po)); Pm[ib * NORB + jb + 1] = 0.5f * (po + pn);
        po = Pm[(ib + 1) * NORB + jb];     pn = acc10; lmax = fmaxf(lmax, fabsf(pn - po)); Pm[(ib + 1) * NORB + jb] = 0.5f * (po + pn);
        po = Pm[(ib + 1) * NORB + jb + 1]; pn = acc11; lmax = fmaxf(lmax, fabsf(pn - po)); Pm[(ib + 1) * NORB + jb + 1] = 0.5f * (po + pn);
    }
    if (last) {
        #pragma unroll
        for (int o = 32; o >= 1; o >>= 1) lmax = fmaxf(lmax, __shfl_xor(lmax, o));
        __shared__ float wm4[4];
        if ((t & 63) == 0) wm4[t >> 6] = lmax;
        __syncthreads();
        if (t == 0) {
            float m = fmaxf(fmaxf(wm4[0], wm4[1]), fmaxf(wm4[2], wm4[3]));
            atomicMax(err + mol, __float_as_uint(m));
        }
    }
}

// ---------------- charge + notconverged ----------------
__global__ void finish_kernel(const int* __restrict__ Z, const float* __restrict__ P,
    const float* __restrict__ errf, float* __restrict__ chg, float* __restrict__ ncv)
{
    int a = blockIdx.x * blockDim.x + threadIdx.x;
    if (a < NATOMS) {
        int mol = a / MOLS, ai = a % MOLS;
        const float* Pm = P + (size_t)mol * MATSZ;
        float tr = 0.0f;
        #pragma unroll
        for (int p = 0; p < 4; ++p) tr += Pm[(4 * ai + p) * NORB + 4 * ai + p];
        chg[a] = (float)(Z[a] - 2) - tr;
    }
    if (a < NMOL) ncv[a] = (errf[a] > 1e-6f) ? 1.0f : 0.0f;
}

extern "C" void kernel_launch(void* const* d_in, const int* in_sizes, int n_in,
                              void* d_out, int out_size, void* d_ws, size_t ws_size,
                              hipStream_t stream)
{
    (void)in_sizes; (void)n_in; (void)out_size; (void)ws_size;

    const int*   nocc   = (const int*)d_in[3];
    const int*   Z      = (const int*)d_in[4];
    const int*   idxi   = (const int*)d_in[9];
    const int*   idxj   = (const int*)d_in[10];
    const float* xij    = (const float*)d_in[13];
    const float* rij    = (const float*)d_in[14];
    const float* zeta_s = (const float*)d_in[15];
    const float* zeta_p = (const float*)d_in[16];
    const float* U_ss   = (const float*)d_in[17];
    const float* U_pp   = (const float*)d_in[18];
    const float* g_ss   = (const float*)d_in[19];
    const float* g_sp   = (const float*)d_in[20];
    const float* g_pp   = (const float*)d_in[21];
    const float* g_p2   = (const float*)d_in[22];
    const float* h_sp   = (const float*)d_in[23];
    const float* beta_s = (const float*)d_in[24];
    const float* beta_p = (const float*)d_in[25];

    float* out     = (float*)d_out;
    float* F_out   = out + F_OFF;
    float* e_out   = out + E_OFF;
    float* P_out   = out + P_OFF;
    float* H_out   = out + H_OFF;
    float* w_out   = out + WMAT_OFF;
    float* chg_out = out + CHG_OFF;
    float* ncv_out = out + NCV_OFF;

    // V basis (37.75MB) lives in the w output region (115.5MB) during SCF;
    // wout_kernel runs LAST to restore the correct w contents.
    float* Vbuf = w_out;

    char* wsb = (char*)d_ws;
    float* Wocc = (float*)wsb;                                  // 37,748,736 B
    float* wss  = (float*)(wsb + 37748736);                     //  1,155,072 B
    float* Ptot = (float*)(wsb + 37748736 + 1155072);           //     49,152 B
    unsigned int* err = (unsigned int*)(wsb + 37748736 + 1155072 + 49152);

    hipMemsetAsync(err, 0, NMOL * sizeof(unsigned int), stream);

    hipFuncSetAttribute(reinterpret_cast<const void*>(eigh_kernel),
                        hipFuncAttributeMaxDynamicSharedMemorySize, EIG_LDS);

    pair_kernel<<<NPAIR / 256, 256, 0, stream>>>(idxi, idxj, xij, rij, zeta_s, zeta_p,
                                                 g_ss, beta_s, beta_p, wss, H_out);
    atom_kernel<<<NATOMS / 256, 256, 0, stream>>>(Z, U_ss, U_pp, wss, H_out);
    pinit_kernel<<<(NMOL * MATSZ) / 256, 256, 0, stream>>>(Z, P_out);

    // R6-validated uniform schedule (unchanged)
    const int sweeps[9] = {14, 8, 8, 8, 8, 8, 8, 8, 6};

    for (int it = 0; it < 9; ++it) {
        ptot_kernel<<<NATOMS / 256, 256, 0, stream>>>(P_out, Ptot);
        fockdiag_kernel<<<NATOMS / 256, 256, 0, stream>>>(P_out, H_out, F_out, Ptot, wss,
                                                          g_ss, g_sp, g_pp, g_p2, h_sp);
        fockoff_kernel<<<NPAIR / 256, 256, 0, stream>>>(idxi, idxj, P_out, H_out, F_out, wss);
        if (it < 8) {
            eigh_kernel<<<NMOL, EIG_T, EIG_LDS, stream>>>(F_out, nocc, Vbuf, Vbuf,
                                                          Wocc, e_out, 0, it > 0 ? 1 : 0,
                                                          sweeps[it]);
            pmix_kernel<<<NMOL * 36, 256, 0, stream>>>(Wocc, nocc, P_out, err, (it == 7) ? 1 : 0);
        } else {
            eigh_kernel<<<NMOL, EIG_T, EIG_LDS, stream>>>(F_out, nocc, Vbuf, Vbuf,
                                                          Wocc, e_out, 1, 1, sweeps[8]);
        }
    }
    finish_kernel<<<NATOMS / 256, 256, 0, stream>>>(Z, P_out, (const float*)err, chg_out, ncv_out);
    wout_kernel<<<(NPAIR * 100) / 256, 256, 0, stream>>>(wss, w_out);
}

// Round 10
// 96999.359 us; speedup vs baseline: 1.0068x; 1.0068x over previous
//
#include <hip/hip_runtime.h>

#define NMOL 256
#define MOLS 48
#define NATOMS 12288           // NMOL*MOLS
#define NORB 192               // 4*MOLS
#define PPM 1128               // pairs per molecule = 48*47/2
#define NPAIR 288768           // NMOL*PPM
#define MATSZ 36864            // NORB*NORB
#define EVC 27.21f

// output offsets (floats)
#define F_OFF   0
#define E_OFF   9437184
#define P_OFF   9486336
#define H_OFF   18923520
#define WMAT_OFF 28360704
#define CHG_OFF 57237504
#define NCV_OFF 57249792

__device__ __forceinline__ int pairoff(int i, int j) {
    return 47 * i - (i * (i - 1)) / 2 + (j - i - 1);
}

// ---------------- per-pair: w_ss + Hcore off-diagonal blocks ----------------
__global__ void pair_kernel(
    const int* __restrict__ idxi, const int* __restrict__ idxj,
    const float* __restrict__ xij, const float* __restrict__ rij,
    const float* __restrict__ zeta_s, const float* __restrict__ zeta_p,
    const float* __restrict__ g_ss,
    const float* __restrict__ beta_s, const float* __restrict__ beta_p,
    float* __restrict__ wss, float* __restrict__ H)
{
    int pp = blockIdx.x * blockDim.x + threadIdx.x;
    if (pp >= NPAIR) return;
    int i = idxi[pp], j = idxj[pp];
    float r = rij[pp];
    float rho = 7.0f / g_ss[i] + 7.0f / g_ss[j];
    float base = 1.0f / sqrtf(r * r + rho * rho);
    float wv = EVC * base;
    wss[pp] = wv;

    float x[3] = { xij[pp * 3 + 0], xij[pp * 3 + 1], xij[pp * 3 + 2] };
    float zsi = zeta_s[i], zpi = zeta_p[i], zsj = zeta_s[j], zpj = zeta_p[j];
    float e_ss = expf(-0.5f * (zsi + zsj) * r);
    float e_sp = expf(-0.5f * (zsi + zpj) * r);
    float e_ps = expf(-0.5f * (zpi + zsj) * r);
    float e_pp = expf(-0.5f * (zpi + zpj) * r);

    float S[4][4];
    S[0][0] = e_ss;
    #pragma unroll
    for (int k = 0; k < 3; ++k) {
        S[0][1 + k] = x[k] * e_sp;
        S[1 + k][0] = -x[k] * e_ps;
        #pragma unroll
        for (int l = 0; l < 3; ++l)
            S[1 + k][1 + l] = ((k == l ? 1.0f : 0.0f) - x[k] * x[l]) * e_pp;
    }
    float boi[4] = { beta_s[i], beta_p[i], beta_p[i], beta_p[i] };
    float boj[4] = { beta_s[j], beta_p[j], beta_p[j], beta_p[j] };

    int mol = i / MOLS, ai = i % MOLS, aj = j % MOLS;
    float* Hm = H + (size_t)mol * MATSZ;
    #pragma unroll
    for (int p = 0; p < 4; ++p)
        #pragma unroll
        for (int q = 0; q < 4; ++q) {
            float v = 0.5f * (boi[p] + boj[q]) * S[p][q];
            Hm[(4 * ai + p) * NORB + 4 * aj + q] = v;
            Hm[(4 * aj + q) * NORB + 4 * ai + p] = v;
        }
}

// ---------------- w output (coalesced) ----------------
__global__ void wout_kernel(const float* __restrict__ wss, float* __restrict__ w_out)
{
    int idx = blockIdx.x * blockDim.x + threadIdx.x;
    if (idx >= NPAIR * 100) return;
    int pp = idx / 100, ab = idx % 100;
    int a = ab / 10, b = ab % 10;
    w_out[idx] = wss[pp] * (1.0f + 0.05f * (float)a) * (1.0f + 0.05f * (float)b);
}

// ---------------- per-atom: vatt gather + Hcore diagonal blocks ----------------
__global__ void atom_kernel(const int* __restrict__ Z,
    const float* __restrict__ U_ss, const float* __restrict__ U_pp,
    const float* __restrict__ wss, float* __restrict__ H)
{
    int a = blockIdx.x * blockDim.x + threadIdx.x;
    if (a >= NATOMS) return;
    int mol = a / MOLS, ai = a % MOLS;
    const float* wm = wss + mol * PPM;
    float vatt = 0.0f;
    for (int j = 0; j < MOLS; ++j) {
        if (j == ai) continue;
        int i_ = ai < j ? ai : j;
        int j_ = ai < j ? j : ai;
        float torej = (float)(Z[mol * MOLS + j] - 2);
        vatt -= torej * wm[pairoff(i_, j_)];
    }
    float u0 = U_ss[a], u1 = U_pp[a];
    float* Hm = H + (size_t)mol * MATSZ;
    #pragma unroll
    for (int p = 0; p < 4; ++p)
        #pragma unroll
        for (int q = 0; q < 4; ++q)
            Hm[(4 * ai + p) * NORB + 4 * ai + q] =
                (p == q) ? ((p == 0 ? u0 : u1) + vatt) : 0.0f;
}

// ---------------- initial density ----------------
__global__ void pinit_kernel(const int* __restrict__ Z, float* __restrict__ P)
{
    int idx = blockIdx.x * blockDim.x + threadIdx.x;
    if (idx >= NMOL * MATSZ) return;
    int mol = idx / MATSZ, rem = idx % MATSZ;
    int r = rem / NORB, c = rem % NORB;
    float v = 0.0f;
    if (r == c) v = (float)(Z[mol * MOLS + r / 4] - 2) * 0.25f;
    P[idx] = v;
}

// ---------------- Ptot (trace of diagonal density block) ----------------
__global__ void ptot_kernel(const float* __restrict__ P, float* __restrict__ Ptot)
{
    int a = blockIdx.x * blockDim.x + threadIdx.x;
    if (a >= NATOMS) return;
    int mol = a / MOLS, ai = a % MOLS;
    const float* Pm = P + (size_t)mol * MATSZ;
    float t = 0.0f;
    #pragma unroll
    for (int p = 0; p < 4; ++p) t += Pm[(4 * ai + p) * NORB + 4 * ai + p];
    Ptot[a] = t;
}

// ---------------- Fock diagonal blocks ----------------
__global__ void fockdiag_kernel(
    const float* __restrict__ P, const float* __restrict__ H, float* __restrict__ F,
    const float* __restrict__ Ptot, const float* __restrict__ wss,
    const float* __restrict__ g_ss, const float* __restrict__ g_sp,
    const float* __restrict__ g_pp, const float* __restrict__ g_p2,
    const float* __restrict__ h_sp)
{
    int a = blockIdx.x * blockDim.x + threadIdx.x;
    if (a >= NATOMS) return;
    int mol = a / MOLS, ai = a % MOLS;
    const float* wm = wss + mol * PPM;
    const float* ptm = Ptot + mol * MOLS;
    float vc = 0.0f;
    for (int j = 0; j < MOLS; ++j) {
        if (j == ai) continue;
        int i_ = ai < j ? ai : j;
        int j_ = ai < j ? j : ai;
        vc += wm[pairoff(i_, j_)] * ptm[j];
    }
    const float* Pm = P + (size_t)mol * MATSZ;
    float Pd[4][4];
    #pragma unroll
    for (int p = 0; p < 4; ++p)
        #pragma unroll
        for (int q = 0; q < 4; ++q)
            Pd[p][q] = Pm[(4 * ai + p) * NORB + 4 * ai + q];

    float Pss = Pd[0][0];
    float Pp0 = Pd[1][1], Pp1 = Pd[2][2], Pp2 = Pd[3][3];
    float Ppp = Pp0 + Pp1 + Pp2;
    float gss = g_ss[a], gsp = g_sp[a], gpp = g_pp[a], gp2 = g_p2[a], hsp = h_sp[a];
    float csp = 1.5f * hsp - 0.5f * gsp;
    float gsp_h = gsp - 0.5f * hsp;
    float fss = 0.5f * Pss * gss + Ppp * gsp_h;
    float cp = 1.25f * gp2 - 0.25f * gpp;
    float fpp0 = Pss * gsp_h + 0.5f * Pp0 * gpp + (Ppp - Pp0) * cp;
    float fpp1 = Pss * gsp_h + 0.5f * Pp1 * gpp + (Ppp - Pp1) * cp;
    float fpp2 = Pss * gsp_h + 0.5f * Pp2 * gpp + (Ppp - Pp2) * cp;
    float coff = 0.75f * gpp - 1.25f * gp2;

    float Fd[4][4];
    Fd[0][0] = fss + vc;
    Fd[1][1] = fpp0 + vc; Fd[2][2] = fpp1 + vc; Fd[3][3] = fpp2 + vc;
    #pragma unroll
    for (int k = 0; k < 3; ++k) {
        Fd[0][1 + k] = Pd[0][1 + k] * csp;
        Fd[1 + k][0] = Pd[1 + k][0] * csp;
    }
    Fd[1][2] = coff * Pd[1][2]; Fd[1][3] = coff * Pd[1][3];
    Fd[2][1] = coff * Pd[2][1]; Fd[2][3] = coff * Pd[2][3];
    Fd[3][1] = coff * Pd[3][1]; Fd[3][2] = coff * Pd[3][2];

    const float* Hm = H + (size_t)mol * MATSZ;
    float* Fm = F + (size_t)mol * MATSZ;
    #pragma unroll
    for (int p = 0; p < 4; ++p)
        #pragma unroll
        for (int q = 0; q < 4; ++q) {
            int ix = (4 * ai + p) * NORB + 4 * ai + q;
            Fm[ix] = Hm[ix] + Fd[p][q];
        }
}

// ---------------- Fock off-diagonal blocks ----------------
__global__ void fockoff_kernel(const int* __restrict__ idxi, const int* __restrict__ idxj,
    const float* __restrict__ P, const float* __restrict__ H, float* __restrict__ F,
    const float* __restrict__ wss)
{
    int pp = blockIdx.x * blockDim.x + threadIdx.x;
    if (pp >= NPAIR) return;
    int i = idxi[pp], j = idxj[pp];
    int mol = i / MOLS, ai = i % MOLS, aj = j % MOLS;
    float wv = wss[pp];
    const float* Pm = P + (size_t)mol * MATSZ;
    const float* Hm = H + (size_t)mol * MATSZ;
    float* Fm = F + (size_t)mol * MATSZ;
    #pragma unroll
    for (int p = 0; p < 4; ++p)
        #pragma unroll
        for (int q = 0; q < 4; ++q) {
            int ij = (4 * ai + p) * NORB + 4 * aj + q;
            int ji = (4 * aj + q) * NORB + 4 * ai + p;
            float f = -0.5f * wv * Pm[ij];
            Fm[ij] = Hm[ij] + f;
            Fm[ji] = Hm[ji] + f;
        }
}

// ---------------- batched eigensolver: one-sided Jacobi on sigma*I - F ----------------
// G=8 super-players (R9 tournament indexing, numerically validated) with REGISTER-SMALL
// QUADRANT processing: per match the 8x8 pair grid is done as 2x2 quadrants of 4x4,
// so the live register set is 4 p-cols + 4 q-cols = 24 floats (+16 norms) instead of
// R9's 48+16, which spilled to scratch at VGPR=84 (R9: 13-28 GB HBM traffic/dispatch).
// p-half loaded once per 2 quadrants, q-half reloaded per quadrant (written back
// between quadrants; same-wave program order, no barrier needed).
// 24 barriers/sweep (vs 48 at G=4); 0.375 col-loads/pair (vs 0.5 at G=4).
#define EIG_T 768
#define ESTR 196     // padded column stride in floats
#define ESTR4 49     // in float4
#define EIG_LDS (( (ESTR*NORB) + 2*NORB ) * 4 + NORB * 4)

__device__ __forceinline__ float rsum64(float v) {
    v += __shfl_xor(v, 1); v += __shfl_xor(v, 2); v += __shfl_xor(v, 4);
    v += __shfl_xor(v, 8); v += __shfl_xor(v, 16); v += __shfl_xor(v, 32);
    return v;
}

// rotate pair (a,b) of 3-float slices if above threshold; exact incremental norms
__device__ __forceinline__ bool jrot3(float d, float& na, float& nb,
                                      float* a, float* b, float tol2) {
    if (d * d > tol2 * na * nb) {
        float zeta = (nb - na) / (2.0f * d);
        float t = copysignf(1.0f, zeta) / (fabsf(zeta) + sqrtf(1.0f + zeta * zeta));
        float cc = 1.0f / sqrtf(1.0f + t * t), ss = t * cc;
        #pragma unroll
        for (int u = 0; u < 3; ++u) {
            float av = a[u], bv = b[u];
            a[u] = cc * av - ss * bv;
            b[u] = ss * av + cc * bv;
        }
        float del = t * d; na -= del; nb += del;
        return true;
    }
    return false;
}

__global__ void __launch_bounds__(EIG_T)
eigh_kernel(const float* __restrict__ Fg, const int* __restrict__ noccA,
            const float* __restrict__ Vin, float* __restrict__ Vout,
            float* __restrict__ Wout, float* __restrict__ eout,
            int mode, int warm, int nsweep)
{
    extern __shared__ float sm[];
    float* B = sm;                          // ESTR*NORB
    float* colv = sm + ESTR * NORB;         // NORB (norms^2, tracked)
    float* colv2 = colv + NORB;             // NORB
    int* slot = (int*)(colv2 + NORB);       // NORB
    __shared__ float sigma;

    const int mol = blockIdx.x;
    const int tid = threadIdx.x;
    const float* Fm = Fg + (size_t)mol * MATSZ;
    float4* B4 = (float4*)B;

    if (!warm) {
        // cold: load F into LDS (padded columns; symmetric so col-major == row-major)
        for (int i4 = tid; i4 < NORB * 48; i4 += EIG_T) {
            int c = i4 / 48, r4 = i4 % 48;
            B4[c * ESTR4 + r4] = ((const float4*)Fm)[i4];
        }
        __syncthreads();
        // Gershgorin per column from LDS (4 lanes per column)
        {
            int c = tid >> 2, part = tid & 3;
            const float4* col = (const float4*)B + c * ESTR4 + part * 12;
            float s = 0.0f;
            #pragma unroll
            for (int u = 0; u < 12; ++u) {
                float4 v = col[u];
                s += fabsf(v.x) + fabsf(v.y) + fabsf(v.z) + fabsf(v.w);
            }
            s += __shfl_xor(s, 1); s += __shfl_xor(s, 2);
            if (part == 0) { float d = B[c * ESTR + c]; colv[c] = s - fabsf(d) + d; }
        }
        __syncthreads();
        if (tid < 64) {
            float m = -3.4e38f;
            for (int i = tid; i < NORB; i += 64) m = fmaxf(m, colv[i]);
            #pragma unroll
            for (int o = 32; o >= 1; o >>= 1) m = fmaxf(m, __shfl_xor(m, o));
            if (tid == 0) sigma = m + 1.0f + 1e-3f * fabsf(m);
        }
        __syncthreads();
        float sg = sigma;
        // B = sigma*I - F
        for (int i4 = tid; i4 < NORB * 48; i4 += EIG_T) {
            int c = i4 / 48, r4 = i4 % 48;
            float4* pv = B4 + c * ESTR4 + r4;
            float4 v = *pv;
            v.x = -v.x; v.y = -v.y; v.z = -v.z; v.w = -v.w;
            *pv = v;
        }
        __syncthreads();
        if (tid < NORB) B[tid * ESTR + tid] += sg;
        __syncthreads();
    } else {
        // warm: load Vprev into LDS
        for (int i4 = tid; i4 < NORB * 48; i4 += EIG_T) {
            int c = i4 / 48, r4 = i4 % 48;
            B4[c * ESTR4 + r4] = ((const float4*)Vin)[(size_t)mol * (MATSZ / 4) + i4];
        }
        // Gershgorin per column from GLOBAL F (no dependency on V load)
        {
            int c = tid >> 2, part = tid & 3;
            const float4* col = (const float4*)(Fm + c * NORB) + part * 12;
            float s = 0.0f;
            #pragma unroll
            for (int u = 0; u < 12; ++u) {
                float4 v = col[u];
                s += fabsf(v.x) + fabsf(v.y) + fabsf(v.z) + fabsf(v.w);
            }
            s += __shfl_xor(s, 1); s += __shfl_xor(s, 2);
            if (part == 0) { float d = Fm[c * NORB + c]; colv[c] = s - fabsf(d) + d; }
        }
        __syncthreads();
        if (tid < 64) {
            float m = -3.4e38f;
            for (int i = tid; i < NORB; i += 64) m = fmaxf(m, colv[i]);
            #pragma unroll
            for (int o = 32; o >= 1; o >>= 1) m = fmaxf(m, __shfl_xor(m, o));
            if (tid == 0) sigma = m + 1.0f + 1e-3f * fabsf(m);
        }
        __syncthreads();
        float sg = sigma;
        // B[:,j] = sg*V[:,j] - F*V[:,j]; 96 teams of 8 lanes, 2 cols each, one pass.
        {
            int t8 = tid >> 3, l8 = tid & 7;
            int j0 = 2 * t8, j1 = j0 + 1;
            float4 acc0[6], acc1[6];
            #pragma unroll
            for (int u = 0; u < 6; ++u) {
                acc0[u].x = acc0[u].y = acc0[u].z = acc0[u].w = 0.0f;
                acc1[u].x = acc1[u].y = acc1[u].z = acc1[u].w = 0.0f;
            }
            const float4* F4 = (const float4*)Fm;
            for (int k = 0; k < NORB; ++k) {
                float v0 = B[j0 * ESTR + k];
                float v1 = B[j1 * ESTR + k];
                const float4* Fk = F4 + k * 48 + l8;
                #pragma unroll
                for (int u = 0; u < 6; ++u) {
                    float4 f = Fk[8 * u];
                    acc0[u].x += f.x * v0; acc0[u].y += f.y * v0;
                    acc0[u].z += f.z * v0; acc0[u].w += f.w * v0;
                    acc1[u].x += f.x * v1; acc1[u].y += f.y * v1;
                    acc1[u].z += f.z * v1; acc1[u].w += f.w * v1;
                }
            }
            #pragma unroll
            for (int u = 0; u < 6; ++u) {
                int r4 = l8 + 8 * u;
                float4* pa = B4 + j0 * ESTR4 + r4;
                float4* pb = B4 + j1 * ESTR4 + r4;
                float4 va = *pa, vb = *pb, oa, ob;
                oa.x = sg * va.x - acc0[u].x; oa.y = sg * va.y - acc0[u].y;
                oa.z = sg * va.z - acc0[u].z; oa.w = sg * va.w - acc0[u].w;
                ob.x = sg * vb.x - acc1[u].x; ob.y = sg * vb.y - acc1[u].y;
                ob.z = sg * vb.z - acc1[u].z; ob.w = sg * vb.w - acc1[u].w;
                *pa = oa; *pb = ob;
            }
        }
        __syncthreads();
    }
    float sg = sigma;

    // exact initial column norms^2 into colv (tracked incrementally during sweeps)
    {
        int c = tid >> 2, part = tid & 3;
        const float4* col = (const float4*)B + c * ESTR4 + part * 12;
        float s = 0.0f;
        #pragma unroll
        for (int u = 0; u < 12; ++u) {
            float4 v = col[u];
            s += v.x * v.x + v.y * v.y + v.z * v.z + v.w * v.w;
        }
        s += __shfl_xor(s, 1); s += __shfl_xor(s, 2);
        if (part == 0) colv[c] = s;
    }
    __syncthreads();

    const float tol2 = 2.5e-11f;   // (5e-6 rel)^2, validated numerics
    const int wv = tid >> 6, lane = tid & 63;   // 12 waves, 64 lanes

    for (int sweep = 0; sweep < nsweep; ++sweep) {
        // ---- 23 cross rounds over 24 players (8 cols each); team = one wave ----
        int p, q;
        if (wv == 0) { p = 23; q = 0; }
        else         { p = wv;  q = 23 - wv; }
        for (int r = 0; r < 23; ++r) {
            float np[8], nq[8];
            #pragma unroll
            for (int i = 0; i < 8; ++i) { np[i] = colv[8 * p + i]; nq[i] = colv[8 * q + i]; }
            // 2x2 quadrants of the 8x8 pair grid; 4 p-cols + 4 q-cols live at a time
            #pragma unroll
            for (int a = 0; a < 2; ++a) {
                float xp[4][3];
                bool tp[4] = {false, false, false, false};
                #pragma unroll
                for (int i = 0; i < 4; ++i) {
                    const float* ap = B + (8 * p + 4 * a + i) * ESTR + 3 * lane;
                    xp[i][0] = ap[0]; xp[i][1] = ap[1]; xp[i][2] = ap[2];
                }
                #pragma unroll
                for (int b = 0; b < 2; ++b) {
                    float xq[4][3];
                    bool tq[4] = {false, false, false, false};
                    #pragma unroll
                    for (int j = 0; j < 4; ++j) {
                        const float* aq = B + (8 * q + 4 * b + j) * ESTR + 3 * lane;
                        xq[j][0] = aq[0]; xq[j][1] = aq[1]; xq[j][2] = aq[2];
                    }
                    #pragma unroll
                    for (int s = 0; s < 4; ++s) {
                        float d[4];
                        #pragma unroll
                        for (int i = 0; i < 4; ++i) {
                            const int j = (i + s) & 3;
                            d[i] = xp[i][0] * xq[j][0] + xp[i][1] * xq[j][1] + xp[i][2] * xq[j][2];
                        }
                        #pragma unroll
                        for (int i = 0; i < 4; ++i) d[i] = rsum64(d[i]);
                        #pragma unroll
                        for (int i = 0; i < 4; ++i) {
                            const int j = (i + s) & 3;
                            if (jrot3(d[i], np[4 * a + i], nq[4 * b + j], xp[i], xq[j], tol2)) {
                                tp[i] = true; tq[j] = true;
                            }
                        }
                    }
                    #pragma unroll
                    for (int j = 0; j < 4; ++j) {
                        if (tq[j]) {
                            float* aq = B + (8 * q + 4 * b + j) * ESTR + 3 * lane;
                            aq[0] = xq[j][0]; aq[1] = xq[j][1]; aq[2] = xq[j][2];
                        }
                    }
                }
                #pragma unroll
                for (int i = 0; i < 4; ++i) {
                    if (tp[i]) {
                        float* ap = B + (8 * p + 4 * a + i) * ESTR + 3 * lane;
                        ap[0] = xp[i][0]; ap[1] = xp[i][1]; ap[2] = xp[i][2];
                    }
                }
            }
            if (lane == 0) {
                #pragma unroll
                for (int i = 0; i < 8; ++i) {
                    colv[8 * p + i] = np[i]; colv[8 * q + i] = nq[i];
                }
            }
            __syncthreads();
            if (wv != 0) p = (p == 22) ? 0 : p + 1;
            q = (q == 22) ? 0 : q + 1;
        }

        // ---- intra-player round: wave w handles players 2w, 2w+1 sequentially ----
        #pragma unroll
        for (int half = 0; half < 2; ++half) {
            const int pl = 2 * wv + half;
            float x[8][3], n[8];
            bool w[8] = {false,false,false,false,false,false,false,false};
            #pragma unroll
            for (int i = 0; i < 8; ++i) {
                const float* aa = B + (8 * pl + i) * ESTR + 3 * lane;
                x[i][0] = aa[0]; x[i][1] = aa[1]; x[i][2] = aa[2];
                n[i] = colv[8 * pl + i];
            }
            // circle method on 8 items: 7 rounds x 4 disjoint pairs
            #pragma unroll
            for (int r7 = 0; r7 < 7; ++r7) {
                const int i0 = r7,            j0 = 7;
                const int i1 = (r7 + 1) % 7,  j1 = (r7 + 6) % 7;
                const int i2 = (r7 + 2) % 7,  j2 = (r7 + 5) % 7;
                const int i3 = (r7 + 3) % 7,  j3 = (r7 + 4) % 7;
                float d[4];
                d[0] = x[i0][0]*x[j0][0] + x[i0][1]*x[j0][1] + x[i0][2]*x[j0][2];
                d[1] = x[i1][0]*x[j1][0] + x[i1][1]*x[j1][1] + x[i1][2]*x[j1][2];
                d[2] = x[i2][0]*x[j2][0] + x[i2][1]*x[j2][1] + x[i2][2]*x[j2][2];
                d[3] = x[i3][0]*x[j3][0] + x[i3][1]*x[j3][1] + x[i3][2]*x[j3][2];
                #pragma unroll
                for (int i = 0; i < 4; ++i) d[i] = rsum64(d[i]);
                if (jrot3(d[0], n[i0], n[j0], x[i0], x[j0], tol2)) { w[i0] = w[j0] = true; }
                if (jrot3(d[1], n[i1], n[j1], x[i1], x[j1], tol2)) { w[i1] = w[j1] = true; }
                if (jrot3(d[2], n[i2], n[j2], x[i2], x[j2], tol2)) { w[i2] = w[j2] = true; }
                if (jrot3(d[3], n[i3], n[j3], x[i3], x[j3], tol2)) { w[i3] = w[j3] = true; }
            }
            #pragma unroll
            for (int i = 0; i < 8; ++i) {
                if (w[i]) {
                    float* aa = B + (8 * pl + i) * ESTR + 3 * lane;
                    aa[0] = x[i][0]; aa[1] = x[i][1]; aa[2] = x[i][2];
                }
            }
            if (lane == 0) {
                #pragma unroll
                for (int i = 0; i < 8; ++i) colv[8 * pl + i] = n[i];
            }
        }
        __syncthreads();
    }

    // exact column norms^2
    {
        int c = tid >> 2, part = tid & 3;
        const float4* col = (const float4*)B + c * ESTR4 + part * 12;
        float s = 0.0f;
        #pragma unroll
        for (int u = 0; u < 12; ++u) {
            float4 v = col[u];
            s += v.x * v.x + v.y * v.y + v.z * v.z + v.w * v.w;
        }
        s += __shfl_xor(s, 1); s += __shfl_xor(s, 2);
        if (part == 0) colv[c] = s;
    }
    __syncthreads();

    if (mode == 0) {
        // occupied = nocc largest norms (= smallest eigenvalues of F)
        int noccm = noccA[mol];
        if (tid < NORB) {
            float nc = colv[tid];
            int rank = 0;
            for (int j2 = 0; j2 < NORB; ++j2) {
                float nj = colv[j2];
                rank += (nj > nc) || (nj == nc && j2 < tid);
            }
            slot[tid] = rank;
            colv2[tid] = rsqrtf(nc);     // 1/||b||
        }
        __syncthreads();
        float* Wm = Wout + (size_t)mol * MATSZ;
        float* Vm = Vout + (size_t)mol * MATSZ;
        for (int i4 = tid; i4 < NORB * 48; i4 += EIG_T) {
            int c = i4 / 48, r4 = i4 % 48;
            float inv = colv2[c];
            float4 v = B4[c * ESTR4 + r4];
            float4 nv;
            nv.x = v.x * inv; nv.y = v.y * inv; nv.z = v.z * inv; nv.w = v.w * inv;
            ((float4*)Vm)[i4] = nv;      // full basis for next warm start
            int sl = slot[c];
            if (sl < noccm) {
                float4 o;
                o.x = nv.x * 1.41421356f; o.y = nv.y * 1.41421356f;
                o.z = nv.z * 1.41421356f; o.w = nv.w * 1.41421356f;
                ((float4*)Wm)[sl * 48 + r4] = o;
            }
        }
    } else {
        // eigenvalues ascending
        if (tid < NORB) colv2[tid] = sg - sqrtf(colv[tid]);
        __syncthreads();
        if (tid < NORB) {
            float ec = colv2[tid];
            int rank = 0;
            for (int j2 = 0; j2 < NORB; ++j2) {
                float ej = colv2[j2];
                rank += (ej < ec) || (ej == ec && j2 < tid);
            }
            eout[mol * NORB + rank] = ec;
        }
    }
}

// ---------------- Pnew = W^T W, mix, err ----------------
__global__ void __launch_bounds__(256)
pmix_kernel(const float* __restrict__ W, const int* __restrict__ noccA,
            float* __restrict__ P, unsigned int* __restrict__ err, int last)
{
    int mol = blockIdx.x / 36;
    int tile = blockIdx.x % 36;
    int i0 = (tile / 6) * 32, j0 = (tile % 6) * 32;
    int K = noccA[mol];
    const float* Wm = W + (size_t)mol * MATSZ;
    __shared__ float As[32][33];
    __shared__ float Bs[32][33];
    int t = threadIdx.x;
    int ty = t >> 4, tx = t & 15;
    float acc00 = 0.f, acc01 = 0.f, acc10 = 0.f, acc11 = 0.f;
    for (int k0 = 0; k0 < K; k0 += 32) {
        for (int l = t; l < 1024; l += 256) {
            int k = l >> 5, idx = l & 31;
            bool ok = (k0 + k) < K;
            As[k][idx] = ok ? Wm[(k0 + k) * NORB + i0 + idx] : 0.0f;
            Bs[k][idx] = ok ? Wm[(k0 + k) * NORB + j0 + idx] : 0.0f;
        }
        __syncthreads();
        #pragma unroll 8
        for (int k = 0; k < 32; ++k) {
            float a0 = As[k][2 * ty], a1 = As[k][2 * ty + 1];
            float b0 = Bs[k][2 * tx], b1 = Bs[k][2 * tx + 1];
            acc00 += a0 * b0; acc01 += a0 * b1; acc10 += a1 * b0; acc11 += a1 * b1;
        }
        __syncthreads();
    }
    float* Pm = P + (size_t)mol * MATSZ;
    float lmax = 0.0f;
    int ib = i0 + 2 * ty, jb = j0 + 2 * tx;
    {
        float po, pn;
        po = Pm[ib * NORB + jb];           pn = acc00; lmax = fmaxf(lmax, fabsf(pn - po)); Pm[ib * NORB + jb] = 0.5f * (po + pn);
        po = Pm[ib * NORB + jb + 1];       pn = acc01; lmax = fmaxf(lmax, fabsf(pn - po)); Pm[ib * NORB + jb + 1] = 0.5f * (po + pn);
        po = Pm[(ib + 1) * NORB + jb];     pn = acc10; lmax = fmaxf(lmax, fabsf(pn - po)); Pm[(ib + 1) * NORB + jb] = 0.5f * (po + pn);
        po = Pm[(ib + 1) * NORB + jb + 1]; pn = acc11; lmax = fmaxf(lmax, fabsf(pn - po)); Pm[(ib + 1) * NORB + jb + 1] = 0.5f * (po + pn);
    }
    if (last) {
        #pragma unroll
        for (int o = 32; o >= 1; o >>= 1) lmax = fmaxf(lmax, __shfl_xor(lmax, o));
        __shared__ float wm4[4];
        if ((t & 63) == 0) wm4[t >> 6] = lmax;
        __syncthreads();
        if (t == 0) {
            float m = fmaxf(fmaxf(wm4[0], wm4[1]), fmaxf(wm4[2], wm4[3]));
            atomicMax(err + mol, __float_as_uint(m));
        }
    }
}

// ---------------- charge + notconverged ----------------
__global__ void finish_kernel(const int* __restrict__ Z, const float* __restrict__ P,
    const float* __restrict__ errf, float* __restrict__ chg, float* __restrict__ ncv)
{
    int a = blockIdx.x * blockDim.x + threadIdx.x;
    if (a < NATOMS) {
        int mol = a / MOLS, ai = a % MOLS;
        const float* Pm = P + (size_t)mol * MATSZ;
        float tr = 0.0f;
        #pragma unroll
        for (int p = 0; p < 4; ++p) tr += Pm[(4 * ai + p) * NORB + 4 * ai + p];
        chg[a] = (float)(Z[a] - 2) - tr;
    }
    if (a < NMOL) ncv[a] = (errf[a] > 1e-6f) ? 1.0f : 0.0f;
}

extern "C" void kernel_launch(void* const* d_in, const int* in_sizes, int n_in,
                              void* d_out, int out_size, void* d_ws, size_t ws_size,
                              hipStream_t stream)
{
    (void)in_sizes; (void)n_in; (void)out_size; (void)ws_size;

    const int*   nocc   = (const int*)d_in[3];
    const int*   Z      = (const int*)d_in[4];
    const int*   idxi   = (const int*)d_in[9];
    const int*   idxj   = (const int*)d_in[10];
    const float* xij    = (const float*)d_in[13];
    const float* rij    = (const float*)d_in[14];
    const float* zeta_s = (const float*)d_in[15];
    const float* zeta_p = (const float*)d_in[16];
    const float* U_ss   = (const float*)d_in[17];
    const float* U_pp   = (const float*)d_in[18];
    const float* g_ss   = (const float*)d_in[19];
    const float* g_sp   = (const float*)d_in[20];
    const float* g_pp   = (const float*)d_in[21];
    const float* g_p2   = (const float*)d_in[22];
    const float* h_sp   = (const float*)d_in[23];
    const float* beta_s = (const float*)d_in[24];
    const float* beta_p = (const float*)d_in[25];

    float* out     = (float*)d_out;
    float* F_out   = out + F_OFF;
    float* e_out   = out + E_OFF;
    float* P_out   = out + P_OFF;
    float* H_out   = out + H_OFF;
    float* w_out   = out + WMAT_OFF;
    float* chg_out = out + CHG_OFF;
    float* ncv_out = out + NCV_OFF;

    // V basis (37.75MB) lives in the w output region (115.5MB) during SCF;
    // wout_kernel runs LAST to restore the correct w contents.
    float* Vbuf = w_out;

    char* wsb = (char*)d_ws;
    float* Wocc = (float*)wsb;                                  // 37,748,736 B
    float* wss  = (float*)(wsb + 37748736);                     //  1,155,072 B
    float* Ptot = (float*)(wsb + 37748736 + 1155072);           //     49,152 B
    unsigned int* err = (unsigned int*)(wsb + 37748736 + 1155072 + 49152);

    hipMemsetAsync(err, 0, NMOL * sizeof(unsigned int), stream);

    hipFuncSetAttribute(reinterpret_cast<const void*>(eigh_kernel),
                        hipFuncAttributeMaxDynamicSharedMemorySize, EIG_LDS);

    pair_kernel<<<NPAIR / 256, 256, 0, stream>>>(idxi, idxj, xij, rij, zeta_s, zeta_p,
                                                 g_ss, beta_s, beta_p, wss, H_out);
    atom_kernel<<<NATOMS / 256, 256, 0, stream>>>(Z, U_ss, U_pp, wss, H_out);
    pinit_kernel<<<(NMOL * MATSZ) / 256, 256, 0, stream>>>(Z, P_out);

    // R6-validated uniform schedule (unchanged)
    const int sweeps[9] = {14, 8, 8, 8, 8, 8, 8, 8, 6};

    for (int it = 0; it < 9; ++it) {
        ptot_kernel<<<NATOMS / 256, 256, 0, stream>>>(P_out, Ptot);
        fockdiag_kernel<<<NATOMS / 256, 256, 0, stream>>>(P_out, H_out, F_out, Ptot, wss,
                                                          g_ss, g_sp, g_pp, g_p2, h_sp);
        fockoff_kernel<<<NPAIR / 256, 256, 0, stream>>>(idxi, idxj, P_out, H_out, F_out, wss);
        if (it < 8) {
            eigh_kernel<<<NMOL, EIG_T, EIG_LDS, stream>>>(F_out, nocc, Vbuf, Vbuf,
                                                          Wocc, e_out, 0, it > 0 ? 1 : 0,
                                                          sweeps[it]);
            pmix_kernel<<<NMOL * 36, 256, 0, stream>>>(Wocc, nocc, P_out, err, (it == 7) ? 1 : 0);
        } else {
            eigh_kernel<<<NMOL, EIG_T, EIG_LDS, stream>>>(F_out, nocc, Vbuf, Vbuf,
                                                          Wocc, e_out, 1, 1, sweeps[8]);
        }
    }
    finish_kernel<<<NATOMS / 256, 256, 0, stream>>>(Z, P_out, (const float*)err, chg_out, ncv_out);
    wout_kernel<<<(NPAIR * 100) / 256, 256, 0, stream>>>(wss, w_out);
}

// Round 11
// 27082.544 us; speedup vs baseline: 3.6059x; 3.5816x over previous
//
#include <hip/hip_runtime.h>

#define NMOL 256
#define MOLS 48
#define NATOMS 12288           // NMOL*MOLS
#define NORB 192               // 4*MOLS
#define PPM 1128               // pairs per molecule = 48*47/2
#define NPAIR 288768           // NMOL*PPM
#define MATSZ 36864            // NORB*NORB
#define EVC 27.21f

// output offsets (floats)
#define F_OFF   0
#define E_OFF   9437184
#define P_OFF   9486336
#define H_OFF   18923520
#define WMAT_OFF 28360704
#define CHG_OFF 57237504
#define NCV_OFF 57249792

__device__ __forceinline__ int pairoff(int i, int j) {
    return 47 * i - (i * (i - 1)) / 2 + (j - i - 1);
}

// ---------------- per-pair: w_ss + Hcore off-diagonal blocks ----------------
__global__ void pair_kernel(
    const int* __restrict__ idxi, const int* __restrict__ idxj,
    const float* __restrict__ xij, const float* __restrict__ rij,
    const float* __restrict__ zeta_s, const float* __restrict__ zeta_p,
    const float* __restrict__ g_ss,
    const float* __restrict__ beta_s, const float* __restrict__ beta_p,
    float* __restrict__ wss, float* __restrict__ H)
{
    int pp = blockIdx.x * blockDim.x + threadIdx.x;
    if (pp >= NPAIR) return;
    int i = idxi[pp], j = idxj[pp];
    float r = rij[pp];
    float rho = 7.0f / g_ss[i] + 7.0f / g_ss[j];
    float base = 1.0f / sqrtf(r * r + rho * rho);
    float wv = EVC * base;
    wss[pp] = wv;

    float x[3] = { xij[pp * 3 + 0], xij[pp * 3 + 1], xij[pp * 3 + 2] };
    float zsi = zeta_s[i], zpi = zeta_p[i], zsj = zeta_s[j], zpj = zeta_p[j];
    float e_ss = expf(-0.5f * (zsi + zsj) * r);
    float e_sp = expf(-0.5f * (zsi + zpj) * r);
    float e_ps = expf(-0.5f * (zpi + zsj) * r);
    float e_pp = expf(-0.5f * (zpi + zpj) * r);

    float S[4][4];
    S[0][0] = e_ss;
    #pragma unroll
    for (int k = 0; k < 3; ++k) {
        S[0][1 + k] = x[k] * e_sp;
        S[1 + k][0] = -x[k] * e_ps;
        #pragma unroll
        for (int l = 0; l < 3; ++l)
            S[1 + k][1 + l] = ((k == l ? 1.0f : 0.0f) - x[k] * x[l]) * e_pp;
    }
    float boi[4] = { beta_s[i], beta_p[i], beta_p[i], beta_p[i] };
    float boj[4] = { beta_s[j], beta_p[j], beta_p[j], beta_p[j] };

    int mol = i / MOLS, ai = i % MOLS, aj = j % MOLS;
    float* Hm = H + (size_t)mol * MATSZ;
    #pragma unroll
    for (int p = 0; p < 4; ++p)
        #pragma unroll
        for (int q = 0; q < 4; ++q) {
            float v = 0.5f * (boi[p] + boj[q]) * S[p][q];
            Hm[(4 * ai + p) * NORB + 4 * aj + q] = v;
            Hm[(4 * aj + q) * NORB + 4 * ai + p] = v;
        }
}

// ---------------- w output (coalesced) ----------------
__global__ void wout_kernel(const float* __restrict__ wss, float* __restrict__ w_out)
{
    int idx = blockIdx.x * blockDim.x + threadIdx.x;
    if (idx >= NPAIR * 100) return;
    int pp = idx / 100, ab = idx % 100;
    int a = ab / 10, b = ab % 10;
    w_out[idx] = wss[pp] * (1.0f + 0.05f * (float)a) * (1.0f + 0.05f * (float)b);
}

// ---------------- per-atom: vatt gather + Hcore diagonal blocks ----------------
__global__ void atom_kernel(const int* __restrict__ Z,
    const float* __restrict__ U_ss, const float* __restrict__ U_pp,
    const float* __restrict__ wss, float* __restrict__ H)
{
    int a = blockIdx.x * blockDim.x + threadIdx.x;
    if (a >= NATOMS) return;
    int mol = a / MOLS, ai = a % MOLS;
    const float* wm = wss + mol * PPM;
    float vatt = 0.0f;
    for (int j = 0; j < MOLS; ++j) {
        if (j == ai) continue;
        int i_ = ai < j ? ai : j;
        int j_ = ai < j ? j : ai;
        float torej = (float)(Z[mol * MOLS + j] - 2);
        vatt -= torej * wm[pairoff(i_, j_)];
    }
    float u0 = U_ss[a], u1 = U_pp[a];
    float* Hm = H + (size_t)mol * MATSZ;
    #pragma unroll
    for (int p = 0; p < 4; ++p)
        #pragma unroll
        for (int q = 0; q < 4; ++q)
            Hm[(4 * ai + p) * NORB + 4 * ai + q] =
                (p == q) ? ((p == 0 ? u0 : u1) + vatt) : 0.0f;
}

// ---------------- initial density ----------------
__global__ void pinit_kernel(const int* __restrict__ Z, float* __restrict__ P)
{
    int idx = blockIdx.x * blockDim.x + threadIdx.x;
    if (idx >= NMOL * MATSZ) return;
    int mol = idx / MATSZ, rem = idx % MATSZ;
    int r = rem / NORB, c = rem % NORB;
    float v = 0.0f;
    if (r == c) v = (float)(Z[mol * MOLS + r / 4] - 2) * 0.25f;
    P[idx] = v;
}

// ---------------- Ptot (trace of diagonal density block) ----------------
__global__ void ptot_kernel(const float* __restrict__ P, float* __restrict__ Ptot)
{
    int a = blockIdx.x * blockDim.x + threadIdx.x;
    if (a >= NATOMS) return;
    int mol = a / MOLS, ai = a % MOLS;
    const float* Pm = P + (size_t)mol * MATSZ;
    float t = 0.0f;
    #pragma unroll
    for (int p = 0; p < 4; ++p) t += Pm[(4 * ai + p) * NORB + 4 * ai + p];
    Ptot[a] = t;
}

// ---------------- Fock diagonal blocks ----------------
__global__ void fockdiag_kernel(
    const float* __restrict__ P, const float* __restrict__ H, float* __restrict__ F,
    const float* __restrict__ Ptot, const float* __restrict__ wss,
    const float* __restrict__ g_ss, const float* __restrict__ g_sp,
    const float* __restrict__ g_pp, const float* __restrict__ g_p2,
    const float* __restrict__ h_sp)
{
    int a = blockIdx.x * blockDim.x + threadIdx.x;
    if (a >= NATOMS) return;
    int mol = a / MOLS, ai = a % MOLS;
    const float* wm = wss + mol * PPM;
    const float* ptm = Ptot + mol * MOLS;
    float vc = 0.0f;
    for (int j = 0; j < MOLS; ++j) {
        if (j == ai) continue;
        int i_ = ai < j ? ai : j;
        int j_ = ai < j ? j : ai;
        vc += wm[pairoff(i_, j_)] * ptm[j];
    }
    const float* Pm = P + (size_t)mol * MATSZ;
    float Pd[4][4];
    #pragma unroll
    for (int p = 0; p < 4; ++p)
        #pragma unroll
        for (int q = 0; q < 4; ++q)
            Pd[p][q] = Pm[(4 * ai + p) * NORB + 4 * ai + q];

    float Pss = Pd[0][0];
    float Pp0 = Pd[1][1], Pp1 = Pd[2][2], Pp2 = Pd[3][3];
    float Ppp = Pp0 + Pp1 + Pp2;
    float gss = g_ss[a], gsp = g_sp[a], gpp = g_pp[a], gp2 = g_p2[a], hsp = h_sp[a];
    float csp = 1.5f * hsp - 0.5f * gsp;
    float gsp_h = gsp - 0.5f * hsp;
    float fss = 0.5f * Pss * gss + Ppp * gsp_h;
    float cp = 1.25f * gp2 - 0.25f * gpp;
    float fpp0 = Pss * gsp_h + 0.5f * Pp0 * gpp + (Ppp - Pp0) * cp;
    float fpp1 = Pss * gsp_h + 0.5f * Pp1 * gpp + (Ppp - Pp1) * cp;
    float fpp2 = Pss * gsp_h + 0.5f * Pp2 * gpp + (Ppp - Pp2) * cp;
    float coff = 0.75f * gpp - 1.25f * gp2;

    float Fd[4][4];
    Fd[0][0] = fss + vc;
    Fd[1][1] = fpp0 + vc; Fd[2][2] = fpp1 + vc; Fd[3][3] = fpp2 + vc;
    #pragma unroll
    for (int k = 0; k < 3; ++k) {
        Fd[0][1 + k] = Pd[0][1 + k] * csp;
        Fd[1 + k][0] = Pd[1 + k][0] * csp;
    }
    Fd[1][2] = coff * Pd[1][2]; Fd[1][3] = coff * Pd[1][3];
    Fd[2][1] = coff * Pd[2][1]; Fd[2][3] = coff * Pd[2][3];
    Fd[3][1] = coff * Pd[3][1]; Fd[3][2] = coff * Pd[3][2];

    const float* Hm = H + (size_t)mol * MATSZ;
    float* Fm = F + (size_t)mol * MATSZ;
    #pragma unroll
    for (int p = 0; p < 4; ++p)
        #pragma unroll
        for (int q = 0; q < 4; ++q) {
            int ix = (4 * ai + p) * NORB + 4 * ai + q;
            Fm[ix] = Hm[ix] + Fd[p][q];
        }
}

// ---------------- Fock off-diagonal blocks ----------------
__global__ void fockoff_kernel(const int* __restrict__ idxi, const int* __restrict__ idxj,
    const float* __restrict__ P, const float* __restrict__ H, float* __restrict__ F,
    const float* __restrict__ wss)
{
    int pp = blockIdx.x * blockDim.x + threadIdx.x;
    if (pp >= NPAIR) return;
    int i = idxi[pp], j = idxj[pp];
    int mol = i / MOLS, ai = i % MOLS, aj = j % MOLS;
    float wv = wss[pp];
    const float* Pm = P + (size_t)mol * MATSZ;
    const float* Hm = H + (size_t)mol * MATSZ;
    float* Fm = F + (size_t)mol * MATSZ;
    #pragma unroll
    for (int p = 0; p < 4; ++p)
        #pragma unroll
        for (int q = 0; q < 4; ++q) {
            int ij = (4 * ai + p) * NORB + 4 * aj + q;
            int ji = (4 * aj + q) * NORB + 4 * ai + p;
            float f = -0.5f * wv * Pm[ij];
            Fm[ij] = Hm[ij] + f;
            Fm[ji] = Hm[ji] + f;
        }
}

// ---------------- batched eigensolver: one-sided Jacobi on sigma*I - F ----------------
// G=4 (R8-validated tournament + phase ordering) with 32-LANE TEAMS:
// 48 players x 4 cols; 24 matches/round x 32 lanes = 768 threads (12 waves, 2x R8
// occupancy). Per-lane slice = 6 floats, stride-32 interleaved (B[c*ESTR+lane+32u]):
// bank=(4c+lane)%32 -> conflict-free within a 32-lane team, 2-way across the wave
// (free, m136). Live register set ~60 floats (fits default 84-VGPR cap; R9/R10's
// G=8 needed 128+ and spilled 8-32 GB to scratch). Rotation ORDER identical to R8
// -> numerics carry over. 48 barriers/sweep.
#define EIG_T 768
#define ESTR 196     // padded column stride in floats
#define ESTR4 49     // in float4
#define EIG_LDS (( (ESTR*NORB) + 2*NORB ) * 4 + NORB * 4)

__device__ __forceinline__ float rsum32(float v) {
    v += __shfl_xor(v, 1); v += __shfl_xor(v, 2); v += __shfl_xor(v, 4);
    v += __shfl_xor(v, 8); v += __shfl_xor(v, 16);
    return v;
}

__device__ __forceinline__ float dot6(const float* a, const float* b) {
    return a[0]*b[0] + a[1]*b[1] + a[2]*b[2] + a[3]*b[3] + a[4]*b[4] + a[5]*b[5];
}

// rotate pair (a,b) of 6-float slices if above threshold; exact incremental norms
__device__ __forceinline__ bool jrot6(float d, float& na, float& nb,
                                      float* a, float* b, float tol2) {
    if (d * d > tol2 * na * nb) {
        float zeta = (nb - na) / (2.0f * d);
        float t = copysignf(1.0f, zeta) / (fabsf(zeta) + sqrtf(1.0f + zeta * zeta));
        float cc = 1.0f / sqrtf(1.0f + t * t), ss = t * cc;
        #pragma unroll
        for (int u = 0; u < 6; ++u) {
            float av = a[u], bv = b[u];
            a[u] = cc * av - ss * bv;
            b[u] = ss * av + cc * bv;
        }
        float del = t * d; na -= del; nb += del;
        return true;
    }
    return false;
}

__global__ void __launch_bounds__(EIG_T)
eigh_kernel(const float* __restrict__ Fg, const int* __restrict__ noccA,
            const float* __restrict__ Vin, float* __restrict__ Vout,
            float* __restrict__ Wout, float* __restrict__ eout,
            int mode, int warm, int nsweep)
{
    extern __shared__ float sm[];
    float* B = sm;                          // ESTR*NORB
    float* colv = sm + ESTR * NORB;         // NORB (norms^2, tracked)
    float* colv2 = colv + NORB;             // NORB
    int* slot = (int*)(colv2 + NORB);       // NORB
    __shared__ float sigma;

    const int mol = blockIdx.x;
    const int tid = threadIdx.x;
    const float* Fm = Fg + (size_t)mol * MATSZ;
    float4* B4 = (float4*)B;

    if (!warm) {
        // cold: load F into LDS (padded columns; symmetric so col-major == row-major)
        for (int i4 = tid; i4 < NORB * 48; i4 += EIG_T) {
            int c = i4 / 48, r4 = i4 % 48;
            B4[c * ESTR4 + r4] = ((const float4*)Fm)[i4];
        }
        __syncthreads();
        // Gershgorin per column from LDS (4 lanes per column)
        {
            int c = tid >> 2, part = tid & 3;
            const float4* col = (const float4*)B + c * ESTR4 + part * 12;
            float s = 0.0f;
            #pragma unroll
            for (int u = 0; u < 12; ++u) {
                float4 v = col[u];
                s += fabsf(v.x) + fabsf(v.y) + fabsf(v.z) + fabsf(v.w);
            }
            s += __shfl_xor(s, 1); s += __shfl_xor(s, 2);
            if (part == 0) { float d = B[c * ESTR + c]; colv[c] = s - fabsf(d) + d; }
        }
        __syncthreads();
        if (tid < 64) {
            float m = -3.4e38f;
            for (int i = tid; i < NORB; i += 64) m = fmaxf(m, colv[i]);
            #pragma unroll
            for (int o = 32; o >= 1; o >>= 1) m = fmaxf(m, __shfl_xor(m, o));
            if (tid == 0) sigma = m + 1.0f + 1e-3f * fabsf(m);
        }
        __syncthreads();
        float sg = sigma;
        // B = sigma*I - F
        for (int i4 = tid; i4 < NORB * 48; i4 += EIG_T) {
            int c = i4 / 48, r4 = i4 % 48;
            float4* pv = B4 + c * ESTR4 + r4;
            float4 v = *pv;
            v.x = -v.x; v.y = -v.y; v.z = -v.z; v.w = -v.w;
            *pv = v;
        }
        __syncthreads();
        if (tid < NORB) B[tid * ESTR + tid] += sg;
        __syncthreads();
    } else {
        // warm: load Vprev into LDS
        for (int i4 = tid; i4 < NORB * 48; i4 += EIG_T) {
            int c = i4 / 48, r4 = i4 % 48;
            B4[c * ESTR4 + r4] = ((const float4*)Vin)[(size_t)mol * (MATSZ / 4) + i4];
        }
        // Gershgorin per column from GLOBAL F (no dependency on V load)
        {
            int c = tid >> 2, part = tid & 3;
            const float4* col = (const float4*)(Fm + c * NORB) + part * 12;
            float s = 0.0f;
            #pragma unroll
            for (int u = 0; u < 12; ++u) {
                float4 v = col[u];
                s += fabsf(v.x) + fabsf(v.y) + fabsf(v.z) + fabsf(v.w);
            }
            s += __shfl_xor(s, 1); s += __shfl_xor(s, 2);
            if (part == 0) { float d = Fm[c * NORB + c]; colv[c] = s - fabsf(d) + d; }
        }
        __syncthreads();
        if (tid < 64) {
            float m = -3.4e38f;
            for (int i = tid; i < NORB; i += 64) m = fmaxf(m, colv[i]);
            #pragma unroll
            for (int o = 32; o >= 1; o >>= 1) m = fmaxf(m, __shfl_xor(m, o));
            if (tid == 0) sigma = m + 1.0f + 1e-3f * fabsf(m);
        }
        __syncthreads();
        float sg = sigma;
        // B[:,j] = sg*V[:,j] - F*V[:,j]; 96 teams of 8 lanes, 2 cols each, one pass.
        {
            int t8 = tid >> 3, l8 = tid & 7;
            int j0 = 2 * t8, j1 = j0 + 1;
            float4 acc0[6], acc1[6];
            #pragma unroll
            for (int u = 0; u < 6; ++u) {
                acc0[u].x = acc0[u].y = acc0[u].z = acc0[u].w = 0.0f;
                acc1[u].x = acc1[u].y = acc1[u].z = acc1[u].w = 0.0f;
            }
            const float4* F4 = (const float4*)Fm;
            for (int k = 0; k < NORB; ++k) {
                float v0 = B[j0 * ESTR + k];
                float v1 = B[j1 * ESTR + k];
                const float4* Fk = F4 + k * 48 + l8;
                #pragma unroll
                for (int u = 0; u < 6; ++u) {
                    float4 f = Fk[8 * u];
                    acc0[u].x += f.x * v0; acc0[u].y += f.y * v0;
                    acc0[u].z += f.z * v0; acc0[u].w += f.w * v0;
                    acc1[u].x += f.x * v1; acc1[u].y += f.y * v1;
                    acc1[u].z += f.z * v1; acc1[u].w += f.w * v1;
                }
            }
            #pragma unroll
            for (int u = 0; u < 6; ++u) {
                int r4 = l8 + 8 * u;
                float4* pa = B4 + j0 * ESTR4 + r4;
                float4* pb = B4 + j1 * ESTR4 + r4;
                float4 va = *pa, vb = *pb, oa, ob;
                oa.x = sg * va.x - acc0[u].x; oa.y = sg * va.y - acc0[u].y;
                oa.z = sg * va.z - acc0[u].z; oa.w = sg * va.w - acc0[u].w;
                ob.x = sg * vb.x - acc1[u].x; ob.y = sg * vb.y - acc1[u].y;
                ob.z = sg * vb.z - acc1[u].z; ob.w = sg * vb.w - acc1[u].w;
                *pa = oa; *pb = ob;
            }
        }
        __syncthreads();
    }
    float sg = sigma;

    // exact initial column norms^2 into colv (tracked incrementally during sweeps)
    {
        int c = tid >> 2, part = tid & 3;
        const float4* col = (const float4*)B + c * ESTR4 + part * 12;
        float s = 0.0f;
        #pragma unroll
        for (int u = 0; u < 12; ++u) {
            float4 v = col[u];
            s += v.x * v.x + v.y * v.y + v.z * v.z + v.w * v.w;
        }
        s += __shfl_xor(s, 1); s += __shfl_xor(s, 2);
        if (part == 0) colv[c] = s;
    }
    __syncthreads();

    const float tol2 = 2.5e-11f;   // (5e-6 rel)^2, validated numerics
    const int team = tid >> 5, lane = tid & 31;   // 24 teams of 32 lanes

    for (int sweep = 0; sweep < nsweep; ++sweep) {
        // ---- 47 cross rounds over 48 players (4 cols each); 24 matches/round ----
        int p, q;
        if (team == 0) { p = 47; q = 0; }
        else           { p = team; q = 47 - team; }
        for (int r = 0; r < 47; ++r) {
            float xp[4][6], xq[4][6];
            float np[4], nq[4];
            bool wp[4] = {false,false,false,false};
            bool wq[4] = {false,false,false,false};
            #pragma unroll
            for (int i = 0; i < 4; ++i) {
                const float* ap = B + (4 * p + i) * ESTR + lane;
                const float* aq = B + (4 * q + i) * ESTR + lane;
                #pragma unroll
                for (int u = 0; u < 6; ++u) { xp[i][u] = ap[32 * u]; xq[i][u] = aq[32 * u]; }
                np[i] = colv[4 * p + i]; nq[i] = colv[4 * q + i];
            }
            // 4 phases of 4 disjoint pairs (p_i, q_{(i+s)&3}) — ordering == R8
            #pragma unroll
            for (int s = 0; s < 4; ++s) {
                float d[4];
                #pragma unroll
                for (int i = 0; i < 4; ++i)
                    d[i] = dot6(xp[i], xq[(i + s) & 3]);
                #pragma unroll
                for (int i = 0; i < 4; ++i)
                    d[i] = rsum32(d[i]);
                #pragma unroll
                for (int i = 0; i < 4; ++i) {
                    int j = (i + s) & 3;
                    if (jrot6(d[i], np[i], nq[j], xp[i], xq[j], tol2)) {
                        wp[i] = true; wq[j] = true;
                    }
                }
            }
            #pragma unroll
            for (int i = 0; i < 4; ++i) {
                if (wp[i]) {
                    float* ap = B + (4 * p + i) * ESTR + lane;
                    #pragma unroll
                    for (int u = 0; u < 6; ++u) ap[32 * u] = xp[i][u];
                }
                if (wq[i]) {
                    float* aq = B + (4 * q + i) * ESTR + lane;
                    #pragma unroll
                    for (int u = 0; u < 6; ++u) aq[32 * u] = xq[i][u];
                }
            }
            if (lane == 0) {
                #pragma unroll
                for (int i = 0; i < 4; ++i) {
                    colv[4 * p + i] = np[i]; colv[4 * q + i] = nq[i];
                }
            }
            __syncthreads();
            if (team != 0) p = (p == 46) ? 0 : p + 1;
            q = (q == 46) ? 0 : q + 1;
        }

        // ---- intra-player round: team handles players 2t, 2t+1 (6 pairs each) ----
        {
            const int plA = 2 * team, plB = plA + 1;
            float xa[4][6], xb[4][6];
            float na[4], nb[4];
            bool wa[4] = {false,false,false,false};
            bool wb[4] = {false,false,false,false};
            #pragma unroll
            for (int i = 0; i < 4; ++i) {
                const float* aa = B + (4 * plA + i) * ESTR + lane;
                const float* ab = B + (4 * plB + i) * ESTR + lane;
                #pragma unroll
                for (int u = 0; u < 6; ++u) { xa[i][u] = aa[32 * u]; xb[i][u] = ab[32 * u]; }
                na[i] = colv[4 * plA + i]; nb[i] = colv[4 * plB + i];
            }
            // 3 phases: (0,1)(2,3) / (0,2)(1,3) / (0,3)(1,2) for both players
            const int pi0[3] = {0, 0, 0}, pj0[3] = {1, 2, 3};
            const int pi1[3] = {2, 1, 1}, pj1[3] = {3, 3, 2};
            #pragma unroll
            for (int s = 0; s < 3; ++s) {
                int i0 = pi0[s], j0 = pj0[s], i1 = pi1[s], j1 = pj1[s];
                float d0 = dot6(xa[i0], xa[j0]);
                float d1 = dot6(xa[i1], xa[j1]);
                float d2 = dot6(xb[i0], xb[j0]);
                float d3 = dot6(xb[i1], xb[j1]);
                d0 = rsum32(d0); d1 = rsum32(d1); d2 = rsum32(d2); d3 = rsum32(d3);
                if (jrot6(d0, na[i0], na[j0], xa[i0], xa[j0], tol2)) { wa[i0] = wa[j0] = true; }
                if (jrot6(d1, na[i1], na[j1], xa[i1], xa[j1], tol2)) { wa[i1] = wa[j1] = true; }
                if (jrot6(d2, nb[i0], nb[j0], xb[i0], xb[j0], tol2)) { wb[i0] = wb[j0] = true; }
                if (jrot6(d3, nb[i1], nb[j1], xb[i1], xb[j1], tol2)) { wb[i1] = wb[j1] = true; }
            }
            #pragma unroll
            for (int i = 0; i < 4; ++i) {
                if (wa[i]) {
                    float* aa = B + (4 * plA + i) * ESTR + lane;
                    #pragma unroll
                    for (int u = 0; u < 6; ++u) aa[32 * u] = xa[i][u];
                }
                if (wb[i]) {
                    float* ab = B + (4 * plB + i) * ESTR + lane;
                    #pragma unroll
                    for (int u = 0; u < 6; ++u) ab[32 * u] = xb[i][u];
                }
            }
            if (lane == 0) {
                #pragma unroll
                for (int i = 0; i < 4; ++i) {
                    colv[4 * plA + i] = na[i]; colv[4 * plB + i] = nb[i];
                }
            }
            __syncthreads();
        }
    }

    // exact column norms^2
    {
        int c = tid >> 2, part = tid & 3;
        const float4* col = (const float4*)B + c * ESTR4 + part * 12;
        float s = 0.0f;
        #pragma unroll
        for (int u = 0; u < 12; ++u) {
            float4 v = col[u];
            s += v.x * v.x + v.y * v.y + v.z * v.z + v.w * v.w;
        }
        s += __shfl_xor(s, 1); s += __shfl_xor(s, 2);
        if (part == 0) colv[c] = s;
    }
    __syncthreads();

    if (mode == 0) {
        // occupied = nocc largest norms (= smallest eigenvalues of F)
        int noccm = noccA[mol];
        if (tid < NORB) {
            float nc = colv[tid];
            int rank = 0;
            for (int j2 = 0; j2 < NORB; ++j2) {
                float nj = colv[j2];
                rank += (nj > nc) || (nj == nc && j2 < tid);
            }
            slot[tid] = rank;
            colv2[tid] = rsqrtf(nc);     // 1/||b||
        }
        __syncthreads();
        float* Wm = Wout + (size_t)mol * MATSZ;
        float* Vm = Vout + (size_t)mol * MATSZ;
        for (int i4 = tid; i4 < NORB * 48; i4 += EIG_T) {
            int c = i4 / 48, r4 = i4 % 48;
            float inv = colv2[c];
            float4 v = B4[c * ESTR4 + r4];
            float4 nv;
            nv.x = v.x * inv; nv.y = v.y * inv; nv.z = v.z * inv; nv.w = v.w * inv;
            ((float4*)Vm)[i4] = nv;      // full basis for next warm start
            int sl = slot[c];
            if (sl < noccm) {
                float4 o;
                o.x = nv.x * 1.41421356f; o.y = nv.y * 1.41421356f;
                o.z = nv.z * 1.41421356f; o.w = nv.w * 1.41421356f;
                ((float4*)Wm)[sl * 48 + r4] = o;
            }
        }
    } else {
        // eigenvalues ascending
        if (tid < NORB) colv2[tid] = sg - sqrtf(colv[tid]);
        __syncthreads();
        if (tid < NORB) {
            float ec = colv2[tid];
            int rank = 0;
            for (int j2 = 0; j2 < NORB; ++j2) {
                float ej = colv2[j2];
                rank += (ej < ec) || (ej == ec && j2 < tid);
            }
            eout[mol * NORB + rank] = ec;
        }
    }
}

// ---------------- Pnew = W^T W, mix, err ----------------
__global__ void __launch_bounds__(256)
pmix_kernel(const float* __restrict__ W, const int* __restrict__ noccA,
            float* __restrict__ P, unsigned int* __restrict__ err, int last)
{
    int mol = blockIdx.x / 36;
    int tile = blockIdx.x % 36;
    int i0 = (tile / 6) * 32, j0 = (tile % 6) * 32;
    int K = noccA[mol];
    const float* Wm = W + (size_t)mol * MATSZ;
    __shared__ float As[32][33];
    __shared__ float Bs[32][33];
    int t = threadIdx.x;
    int ty = t >> 4, tx = t & 15;
    float acc00 = 0.f, acc01 = 0.f, acc10 = 0.f, acc11 = 0.f;
    for (int k0 = 0; k0 < K; k0 += 32) {
        for (int l = t; l < 1024; l += 256) {
            int k = l >> 5, idx = l & 31;
            bool ok = (k0 + k) < K;
            As[k][idx] = ok ? Wm[(k0 + k) * NORB + i0 + idx] : 0.0f;
            Bs[k][idx] = ok ? Wm[(k0 + k) * NORB + j0 + idx] : 0.0f;
        }
        __syncthreads();
        #pragma unroll 8
        for (int k = 0; k < 32; ++k) {
            float a0 = As[k][2 * ty], a1 = As[k][2 * ty + 1];
            float b0 = Bs[k][2 * tx], b1 = Bs[k][2 * tx + 1];
            acc00 += a0 * b0; acc01 += a0 * b1; acc10 += a1 * b0; acc11 += a1 * b1;
        }
        __syncthreads();
    }
    float* Pm = P + (size_t)mol * MATSZ;
    float lmax = 0.0f;
    int ib = i0 + 2 * ty, jb = j0 + 2 * tx;
    {
        float po, pn;
        po = Pm[ib * NORB + jb];           pn = acc00; lmax = fmaxf(lmax, fabsf(pn - po)); Pm[ib * NORB + jb] = 0.5f * (po + pn);
        po = Pm[ib * NORB + jb + 1];       pn = acc01; lmax = fmaxf(lmax, fabsf(pn - po)); Pm[ib * NORB + jb + 1] = 0.5f * (po + pn);
        po = Pm[(ib + 1) * NORB + jb];     pn = acc10; lmax = fmaxf(lmax, fabsf(pn - po)); Pm[(ib + 1) * NORB + jb] = 0.5f * (po + pn);
        po = Pm[(ib + 1) * NORB + jb + 1]; pn = acc11; lmax = fmaxf(lmax, fabsf(pn - po)); Pm[(ib + 1) * NORB + jb + 1] = 0.5f * (po + pn);
    }
    if (last) {
        #pragma unroll
        for (int o = 32; o >= 1; o >>= 1) lmax = fmaxf(lmax, __shfl_xor(lmax, o));
        __shared__ float wm4[4];
        if ((t & 63) == 0) wm4[t >> 6] = lmax;
        __syncthreads();
        if (t == 0) {
            float m = fmaxf(fmaxf(wm4[0], wm4[1]), fmaxf(wm4[2], wm4[3]));
            atomicMax(err + mol, __float_as_uint(m));
        }
    }
}

// ---------------- charge + notconverged ----------------
__global__ void finish_kernel(const int* __restrict__ Z, const float* __restrict__ P,
    const float* __restrict__ errf, float* __restrict__ chg, float* __restrict__ ncv)
{
    int a = blockIdx.x * blockDim.x + threadIdx.x;
    if (a < NATOMS) {
        int mol = a / MOLS, ai = a % MOLS;
        const float* Pm = P + (size_t)mol * MATSZ;
        float tr = 0.0f;
        #pragma unroll
        for (int p = 0; p < 4; ++p) tr += Pm[(4 * ai + p) * NORB + 4 * ai + p];
        chg[a] = (float)(Z[a] - 2) - tr;
    }
    if (a < NMOL) ncv[a] = (errf[a] > 1e-6f) ? 1.0f : 0.0f;
}

extern "C" void kernel_launch(void* const* d_in, const int* in_sizes, int n_in,
                              void* d_out, int out_size, void* d_ws, size_t ws_size,
                              hipStream_t stream)
{
    (void)in_sizes; (void)n_in; (void)out_size; (void)ws_size;

    const int*   nocc   = (const int*)d_in[3];
    const int*   Z      = (const int*)d_in[4];
    const int*   idxi   = (const int*)d_in[9];
    const int*   idxj   = (const int*)d_in[10];
    const float* xij    = (const float*)d_in[13];
    const float* rij    = (const float*)d_in[14];
    const float* zeta_s = (const float*)d_in[15];
    const float* zeta_p = (const float*)d_in[16];
    const float* U_ss   = (const float*)d_in[17];
    const float* U_pp   = (const float*)d_in[18];
    const float* g_ss   = (const float*)d_in[19];
    const float* g_sp   = (const float*)d_in[20];
    const float* g_pp   = (const float*)d_in[21];
    const float* g_p2   = (const float*)d_in[22];
    const float* h_sp   = (const float*)d_in[23];
    const float* beta_s = (const float*)d_in[24];
    const float* beta_p = (const float*)d_in[25];

    float* out     = (float*)d_out;
    float* F_out   = out + F_OFF;
    float* e_out   = out + E_OFF;
    float* P_out   = out + P_OFF;
    float* H_out   = out + H_OFF;
    float* w_out   = out + WMAT_OFF;
    float* chg_out = out + CHG_OFF;
    float* ncv_out = out + NCV_OFF;

    // V basis (37.75MB) lives in the w output region (115.5MB) during SCF;
    // wout_kernel runs LAST to restore the correct w contents.
    float* Vbuf = w_out;

    char* wsb = (char*)d_ws;
    float* Wocc = (float*)wsb;                                  // 37,748,736 B
    float* wss  = (float*)(wsb + 37748736);                     //  1,155,072 B
    float* Ptot = (float*)(wsb + 37748736 + 1155072);           //     49,152 B
    unsigned int* err = (unsigned int*)(wsb + 37748736 + 1155072 + 49152);

    hipMemsetAsync(err, 0, NMOL * sizeof(unsigned int), stream);

    hipFuncSetAttribute(reinterpret_cast<const void*>(eigh_kernel),
                        hipFuncAttributeMaxDynamicSharedMemorySize, EIG_LDS);

    pair_kernel<<<NPAIR / 256, 256, 0, stream>>>(idxi, idxj, xij, rij, zeta_s, zeta_p,
                                                 g_ss, beta_s, beta_p, wss, H_out);
    atom_kernel<<<NATOMS / 256, 256, 0, stream>>>(Z, U_ss, U_pp, wss, H_out);
    pinit_kernel<<<(NMOL * MATSZ) / 256, 256, 0, stream>>>(Z, P_out);

    // R6-validated uniform schedule (unchanged)
    const int sweeps[9] = {14, 8, 8, 8, 8, 8, 8, 8, 6};

    for (int it = 0; it < 9; ++it) {
        ptot_kernel<<<NATOMS / 256, 256, 0, stream>>>(P_out, Ptot);
        fockdiag_kernel<<<NATOMS / 256, 256, 0, stream>>>(P_out, H_out, F_out, Ptot, wss,
                                                          g_ss, g_sp, g_pp, g_p2, h_sp);
        fockoff_kernel<<<NPAIR / 256, 256, 0, stream>>>(idxi, idxj, P_out, H_out, F_out, wss);
        if (it < 8) {
            eigh_kernel<<<NMOL, EIG_T, EIG_LDS, stream>>>(F_out, nocc, Vbuf, Vbuf,
                                                          Wocc, e_out, 0, it > 0 ? 1 : 0,
                                                          sweeps[it]);
            pmix_kernel<<<NMOL * 36, 256, 0, stream>>>(Wocc, nocc, P_out, err, (it == 7) ? 1 : 0);
        } else {
            eigh_kernel<<<NMOL, EIG_T, EIG_LDS, stream>>>(F_out, nocc, Vbuf, Vbuf,
                                                          Wocc, e_out, 1, 1, sweeps[8]);
        }
    }
    finish_kernel<<<NATOMS / 256, 256, 0, stream>>>(Z, P_out, (const float*)err, chg_out, ncv_out);
    wout_kernel<<<(NPAIR * 100) / 256, 256, 0, stream>>>(wss, w_out);
}

// Round 12
// 24376.106 us; speedup vs baseline: 4.0062x; 1.1110x over previous
//
#include <hip/hip_runtime.h>

#define NMOL 256
#define MOLS 48
#define NATOMS 12288           // NMOL*MOLS
#define NORB 192               // 4*MOLS
#define PPM 1128               // pairs per molecule = 48*47/2
#define NPAIR 288768           // NMOL*PPM
#define MATSZ 36864            // NORB*NORB
#define EVC 27.21f

// output offsets (floats)
#define F_OFF   0
#define E_OFF   9437184
#define P_OFF   9486336
#define H_OFF   18923520
#define WMAT_OFF 28360704
#define CHG_OFF 57237504
#define NCV_OFF 57249792

__device__ __forceinline__ int pairoff(int i, int j) {
    return 47 * i - (i * (i - 1)) / 2 + (j - i - 1);
}

// ---------------- per-pair: w_ss + Hcore off-diagonal blocks ----------------
__global__ void pair_kernel(
    const int* __restrict__ idxi, const int* __restrict__ idxj,
    const float* __restrict__ xij, const float* __restrict__ rij,
    const float* __restrict__ zeta_s, const float* __restrict__ zeta_p,
    const float* __restrict__ g_ss,
    const float* __restrict__ beta_s, const float* __restrict__ beta_p,
    float* __restrict__ wss, float* __restrict__ H)
{
    int pp = blockIdx.x * blockDim.x + threadIdx.x;
    if (pp >= NPAIR) return;
    int i = idxi[pp], j = idxj[pp];
    float r = rij[pp];
    float rho = 7.0f / g_ss[i] + 7.0f / g_ss[j];
    float base = 1.0f / sqrtf(r * r + rho * rho);
    float wv = EVC * base;
    wss[pp] = wv;

    float x[3] = { xij[pp * 3 + 0], xij[pp * 3 + 1], xij[pp * 3 + 2] };
    float zsi = zeta_s[i], zpi = zeta_p[i], zsj = zeta_s[j], zpj = zeta_p[j];
    float e_ss = expf(-0.5f * (zsi + zsj) * r);
    float e_sp = expf(-0.5f * (zsi + zpj) * r);
    float e_ps = expf(-0.5f * (zpi + zsj) * r);
    float e_pp = expf(-0.5f * (zpi + zpj) * r);

    float S[4][4];
    S[0][0] = e_ss;
    #pragma unroll
    for (int k = 0; k < 3; ++k) {
        S[0][1 + k] = x[k] * e_sp;
        S[1 + k][0] = -x[k] * e_ps;
        #pragma unroll
        for (int l = 0; l < 3; ++l)
            S[1 + k][1 + l] = ((k == l ? 1.0f : 0.0f) - x[k] * x[l]) * e_pp;
    }
    float boi[4] = { beta_s[i], beta_p[i], beta_p[i], beta_p[i] };
    float boj[4] = { beta_s[j], beta_p[j], beta_p[j], beta_p[j] };

    int mol = i / MOLS, ai = i % MOLS, aj = j % MOLS;
    float* Hm = H + (size_t)mol * MATSZ;
    #pragma unroll
    for (int p = 0; p < 4; ++p)
        #pragma unroll
        for (int q = 0; q < 4; ++q) {
            float v = 0.5f * (boi[p] + boj[q]) * S[p][q];
            Hm[(4 * ai + p) * NORB + 4 * aj + q] = v;
            Hm[(4 * aj + q) * NORB + 4 * ai + p] = v;
        }
}

// ---------------- w output (coalesced) ----------------
__global__ void wout_kernel(const float* __restrict__ wss, float* __restrict__ w_out)
{
    int idx = blockIdx.x * blockDim.x + threadIdx.x;
    if (idx >= NPAIR * 100) return;
    int pp = idx / 100, ab = idx % 100;
    int a = ab / 10, b = ab % 10;
    w_out[idx] = wss[pp] * (1.0f + 0.05f * (float)a) * (1.0f + 0.05f * (float)b);
}

// ---------------- per-atom: vatt gather + Hcore diagonal blocks ----------------
__global__ void atom_kernel(const int* __restrict__ Z,
    const float* __restrict__ U_ss, const float* __restrict__ U_pp,
    const float* __restrict__ wss, float* __restrict__ H)
{
    int a = blockIdx.x * blockDim.x + threadIdx.x;
    if (a >= NATOMS) return;
    int mol = a / MOLS, ai = a % MOLS;
    const float* wm = wss + mol * PPM;
    float vatt = 0.0f;
    for (int j = 0; j < MOLS; ++j) {
        if (j == ai) continue;
        int i_ = ai < j ? ai : j;
        int j_ = ai < j ? j : ai;
        float torej = (float)(Z[mol * MOLS + j] - 2);
        vatt -= torej * wm[pairoff(i_, j_)];
    }
    float u0 = U_ss[a], u1 = U_pp[a];
    float* Hm = H + (size_t)mol * MATSZ;
    #pragma unroll
    for (int p = 0; p < 4; ++p)
        #pragma unroll
        for (int q = 0; q < 4; ++q)
            Hm[(4 * ai + p) * NORB + 4 * ai + q] =
                (p == q) ? ((p == 0 ? u0 : u1) + vatt) : 0.0f;
}

// ---------------- initial density ----------------
__global__ void pinit_kernel(const int* __restrict__ Z, float* __restrict__ P)
{
    int idx = blockIdx.x * blockDim.x + threadIdx.x;
    if (idx >= NMOL * MATSZ) return;
    int mol = idx / MATSZ, rem = idx % MATSZ;
    int r = rem / NORB, c = rem % NORB;
    float v = 0.0f;
    if (r == c) v = (float)(Z[mol * MOLS + r / 4] - 2) * 0.25f;
    P[idx] = v;
}

// ---------------- Ptot (trace of diagonal density block) ----------------
__global__ void ptot_kernel(const float* __restrict__ P, float* __restrict__ Ptot)
{
    int a = blockIdx.x * blockDim.x + threadIdx.x;
    if (a >= NATOMS) return;
    int mol = a / MOLS, ai = a % MOLS;
    const float* Pm = P + (size_t)mol * MATSZ;
    float t = 0.0f;
    #pragma unroll
    for (int p = 0; p < 4; ++p) t += Pm[(4 * ai + p) * NORB + 4 * ai + p];
    Ptot[a] = t;
}

// ---------------- Fock diagonal blocks ----------------
__global__ void fockdiag_kernel(
    const float* __restrict__ P, const float* __restrict__ H, float* __restrict__ F,
    const float* __restrict__ Ptot, const float* __restrict__ wss,
    const float* __restrict__ g_ss, const float* __restrict__ g_sp,
    const float* __restrict__ g_pp, const float* __restrict__ g_p2,
    const float* __restrict__ h_sp)
{
    int a = blockIdx.x * blockDim.x + threadIdx.x;
    if (a >= NATOMS) return;
    int mol = a / MOLS, ai = a % MOLS;
    const float* wm = wss + mol * PPM;
    const float* ptm = Ptot + mol * MOLS;
    float vc = 0.0f;
    for (int j = 0; j < MOLS; ++j) {
        if (j == ai) continue;
        int i_ = ai < j ? ai : j;
        int j_ = ai < j ? j : ai;
        vc += wm[pairoff(i_, j_)] * ptm[j];
    }
    const float* Pm = P + (size_t)mol * MATSZ;
    float Pd[4][4];
    #pragma unroll
    for (int p = 0; p < 4; ++p)
        #pragma unroll
        for (int q = 0; q < 4; ++q)
            Pd[p][q] = Pm[(4 * ai + p) * NORB + 4 * ai + q];

    float Pss = Pd[0][0];
    float Pp0 = Pd[1][1], Pp1 = Pd[2][2], Pp2 = Pd[3][3];
    float Ppp = Pp0 + Pp1 + Pp2;
    float gss = g_ss[a], gsp = g_sp[a], gpp = g_pp[a], gp2 = g_p2[a], hsp = h_sp[a];
    float csp = 1.5f * hsp - 0.5f * gsp;
    float gsp_h = gsp - 0.5f * hsp;
    float fss = 0.5f * Pss * gss + Ppp * gsp_h;
    float cp = 1.25f * gp2 - 0.25f * gpp;
    float fpp0 = Pss * gsp_h + 0.5f * Pp0 * gpp + (Ppp - Pp0) * cp;
    float fpp1 = Pss * gsp_h + 0.5f * Pp1 * gpp + (Ppp - Pp1) * cp;
    float fpp2 = Pss * gsp_h + 0.5f * Pp2 * gpp + (Ppp - Pp2) * cp;
    float coff = 0.75f * gpp - 1.25f * gp2;

    float Fd[4][4];
    Fd[0][0] = fss + vc;
    Fd[1][1] = fpp0 + vc; Fd[2][2] = fpp1 + vc; Fd[3][3] = fpp2 + vc;
    #pragma unroll
    for (int k = 0; k < 3; ++k) {
        Fd[0][1 + k] = Pd[0][1 + k] * csp;
        Fd[1 + k][0] = Pd[1 + k][0] * csp;
    }
    Fd[1][2] = coff * Pd[1][2]; Fd[1][3] = coff * Pd[1][3];
    Fd[2][1] = coff * Pd[2][1]; Fd[2][3] = coff * Pd[2][3];
    Fd[3][1] = coff * Pd[3][1]; Fd[3][2] = coff * Pd[3][2];

    const float* Hm = H + (size_t)mol * MATSZ;
    float* Fm = F + (size_t)mol * MATSZ;
    #pragma unroll
    for (int p = 0; p < 4; ++p)
        #pragma unroll
        for (int q = 0; q < 4; ++q) {
            int ix = (4 * ai + p) * NORB + 4 * ai + q;
            Fm[ix] = Hm[ix] + Fd[p][q];
        }
}

// ---------------- Fock off-diagonal blocks ----------------
__global__ void fockoff_kernel(const int* __restrict__ idxi, const int* __restrict__ idxj,
    const float* __restrict__ P, const float* __restrict__ H, float* __restrict__ F,
    const float* __restrict__ wss)
{
    int pp = blockIdx.x * blockDim.x + threadIdx.x;
    if (pp >= NPAIR) return;
    int i = idxi[pp], j = idxj[pp];
    int mol = i / MOLS, ai = i % MOLS, aj = j % MOLS;
    float wv = wss[pp];
    const float* Pm = P + (size_t)mol * MATSZ;
    const float* Hm = H + (size_t)mol * MATSZ;
    float* Fm = F + (size_t)mol * MATSZ;
    #pragma unroll
    for (int p = 0; p < 4; ++p)
        #pragma unroll
        for (int q = 0; q < 4; ++q) {
            int ij = (4 * ai + p) * NORB + 4 * aj + q;
            int ji = (4 * aj + q) * NORB + 4 * ai + p;
            float f = -0.5f * wv * Pm[ij];
            Fm[ij] = Hm[ij] + f;
            Fm[ji] = Hm[ji] + f;
        }
}

// ---------------- batched eigensolver: one-sided Jacobi on sigma*I - F ----------------
// R11-validated structure (G=4, 32-lane teams, 768 threads, 12 waves, no spill).
// This round's single variable: sweep schedule {14,8x7,6} -> {12,6x6,8,5}.
// Accuracy data: mid-sweeps 4 -> absmax 35-84 (R4/R5); mid 8 -> 6.1 (R11);
// mid 6 predicted ~10-20 (threshold 36.5). it0=12 (cold convergence),
// it7=8 (P_7 feeds F_out directly).
#define EIG_T 768
#define ESTR 196     // padded column stride in floats
#define ESTR4 49     // in float4
#define EIG_LDS (( (ESTR*NORB) + 2*NORB ) * 4 + NORB * 4)

__device__ __forceinline__ float rsum32(float v) {
    v += __shfl_xor(v, 1); v += __shfl_xor(v, 2); v += __shfl_xor(v, 4);
    v += __shfl_xor(v, 8); v += __shfl_xor(v, 16);
    return v;
}

__device__ __forceinline__ float dot6(const float* a, const float* b) {
    return a[0]*b[0] + a[1]*b[1] + a[2]*b[2] + a[3]*b[3] + a[4]*b[4] + a[5]*b[5];
}

// rotate pair (a,b) of 6-float slices if above threshold; exact incremental norms
__device__ __forceinline__ bool jrot6(float d, float& na, float& nb,
                                      float* a, float* b, float tol2) {
    if (d * d > tol2 * na * nb) {
        float zeta = (nb - na) / (2.0f * d);
        float t = copysignf(1.0f, zeta) / (fabsf(zeta) + sqrtf(1.0f + zeta * zeta));
        float cc = 1.0f / sqrtf(1.0f + t * t), ss = t * cc;
        #pragma unroll
        for (int u = 0; u < 6; ++u) {
            float av = a[u], bv = b[u];
            a[u] = cc * av - ss * bv;
            b[u] = ss * av + cc * bv;
        }
        float del = t * d; na -= del; nb += del;
        return true;
    }
    return false;
}

__global__ void __launch_bounds__(EIG_T)
eigh_kernel(const float* __restrict__ Fg, const int* __restrict__ noccA,
            const float* __restrict__ Vin, float* __restrict__ Vout,
            float* __restrict__ Wout, float* __restrict__ eout,
            int mode, int warm, int nsweep)
{
    extern __shared__ float sm[];
    float* B = sm;                          // ESTR*NORB
    float* colv = sm + ESTR * NORB;         // NORB (norms^2, tracked)
    float* colv2 = colv + NORB;             // NORB
    int* slot = (int*)(colv2 + NORB);       // NORB
    __shared__ float sigma;

    const int mol = blockIdx.x;
    const int tid = threadIdx.x;
    const float* Fm = Fg + (size_t)mol * MATSZ;
    float4* B4 = (float4*)B;

    if (!warm) {
        // cold: load F into LDS (padded columns; symmetric so col-major == row-major)
        for (int i4 = tid; i4 < NORB * 48; i4 += EIG_T) {
            int c = i4 / 48, r4 = i4 % 48;
            B4[c * ESTR4 + r4] = ((const float4*)Fm)[i4];
        }
        __syncthreads();
        // Gershgorin per column from LDS (4 lanes per column)
        {
            int c = tid >> 2, part = tid & 3;
            const float4* col = (const float4*)B + c * ESTR4 + part * 12;
            float s = 0.0f;
            #pragma unroll
            for (int u = 0; u < 12; ++u) {
                float4 v = col[u];
                s += fabsf(v.x) + fabsf(v.y) + fabsf(v.z) + fabsf(v.w);
            }
            s += __shfl_xor(s, 1); s += __shfl_xor(s, 2);
            if (part == 0) { float d = B[c * ESTR + c]; colv[c] = s - fabsf(d) + d; }
        }
        __syncthreads();
        if (tid < 64) {
            float m = -3.4e38f;
            for (int i = tid; i < NORB; i += 64) m = fmaxf(m, colv[i]);
            #pragma unroll
            for (int o = 32; o >= 1; o >>= 1) m = fmaxf(m, __shfl_xor(m, o));
            if (tid == 0) sigma = m + 1.0f + 1e-3f * fabsf(m);
        }
        __syncthreads();
        float sg = sigma;
        // B = sigma*I - F
        for (int i4 = tid; i4 < NORB * 48; i4 += EIG_T) {
            int c = i4 / 48, r4 = i4 % 48;
            float4* pv = B4 + c * ESTR4 + r4;
            float4 v = *pv;
            v.x = -v.x; v.y = -v.y; v.z = -v.z; v.w = -v.w;
            *pv = v;
        }
        __syncthreads();
        if (tid < NORB) B[tid * ESTR + tid] += sg;
        __syncthreads();
    } else {
        // warm: load Vprev into LDS
        for (int i4 = tid; i4 < NORB * 48; i4 += EIG_T) {
            int c = i4 / 48, r4 = i4 % 48;
            B4[c * ESTR4 + r4] = ((const float4*)Vin)[(size_t)mol * (MATSZ / 4) + i4];
        }
        // Gershgorin per column from GLOBAL F (no dependency on V load)
        {
            int c = tid >> 2, part = tid & 3;
            const float4* col = (const float4*)(Fm + c * NORB) + part * 12;
            float s = 0.0f;
            #pragma unroll
            for (int u = 0; u < 12; ++u) {
                float4 v = col[u];
                s += fabsf(v.x) + fabsf(v.y) + fabsf(v.z) + fabsf(v.w);
            }
            s += __shfl_xor(s, 1); s += __shfl_xor(s, 2);
            if (part == 0) { float d = Fm[c * NORB + c]; colv[c] = s - fabsf(d) + d; }
        }
        __syncthreads();
        if (tid < 64) {
            float m = -3.4e38f;
            for (int i = tid; i < NORB; i += 64) m = fmaxf(m, colv[i]);
            #pragma unroll
            for (int o = 32; o >= 1; o >>= 1) m = fmaxf(m, __shfl_xor(m, o));
            if (tid == 0) sigma = m + 1.0f + 1e-3f * fabsf(m);
        }
        __syncthreads();
        float sg = sigma;
        // B[:,j] = sg*V[:,j] - F*V[:,j]; 96 teams of 8 lanes, 2 cols each, one pass.
        {
            int t8 = tid >> 3, l8 = tid & 7;
            int j0 = 2 * t8, j1 = j0 + 1;
            float4 acc0[6], acc1[6];
            #pragma unroll
            for (int u = 0; u < 6; ++u) {
                acc0[u].x = acc0[u].y = acc0[u].z = acc0[u].w = 0.0f;
                acc1[u].x = acc1[u].y = acc1[u].z = acc1[u].w = 0.0f;
            }
            const float4* F4 = (const float4*)Fm;
            for (int k = 0; k < NORB; ++k) {
                float v0 = B[j0 * ESTR + k];
                float v1 = B[j1 * ESTR + k];
                const float4* Fk = F4 + k * 48 + l8;
                #pragma unroll
                for (int u = 0; u < 6; ++u) {
                    float4 f = Fk[8 * u];
                    acc0[u].x += f.x * v0; acc0[u].y += f.y * v0;
                    acc0[u].z += f.z * v0; acc0[u].w += f.w * v0;
                    acc1[u].x += f.x * v1; acc1[u].y += f.y * v1;
                    acc1[u].z += f.z * v1; acc1[u].w += f.w * v1;
                }
            }
            #pragma unroll
            for (int u = 0; u < 6; ++u) {
                int r4 = l8 + 8 * u;
                float4* pa = B4 + j0 * ESTR4 + r4;
                float4* pb = B4 + j1 * ESTR4 + r4;
                float4 va = *pa, vb = *pb, oa, ob;
                oa.x = sg * va.x - acc0[u].x; oa.y = sg * va.y - acc0[u].y;
                oa.z = sg * va.z - acc0[u].z; oa.w = sg * va.w - acc0[u].w;
                ob.x = sg * vb.x - acc1[u].x; ob.y = sg * vb.y - acc1[u].y;
                ob.z = sg * vb.z - acc1[u].z; ob.w = sg * vb.w - acc1[u].w;
                *pa = oa; *pb = ob;
            }
        }
        __syncthreads();
    }
    float sg = sigma;

    // exact initial column norms^2 into colv (tracked incrementally during sweeps)
    {
        int c = tid >> 2, part = tid & 3;
        const float4* col = (const float4*)B + c * ESTR4 + part * 12;
        float s = 0.0f;
        #pragma unroll
        for (int u = 0; u < 12; ++u) {
            float4 v = col[u];
            s += v.x * v.x + v.y * v.y + v.z * v.z + v.w * v.w;
        }
        s += __shfl_xor(s, 1); s += __shfl_xor(s, 2);
        if (part == 0) colv[c] = s;
    }
    __syncthreads();

    const float tol2 = 2.5e-11f;   // (5e-6 rel)^2, validated numerics
    const int team = tid >> 5, lane = tid & 31;   // 24 teams of 32 lanes

    for (int sweep = 0; sweep < nsweep; ++sweep) {
        // ---- 47 cross rounds over 48 players (4 cols each); 24 matches/round ----
        int p, q;
        if (team == 0) { p = 47; q = 0; }
        else           { p = team; q = 47 - team; }
        for (int r = 0; r < 47; ++r) {
            float xp[4][6], xq[4][6];
            float np[4], nq[4];
            bool wp[4] = {false,false,false,false};
            bool wq[4] = {false,false,false,false};
            #pragma unroll
            for (int i = 0; i < 4; ++i) {
                const float* ap = B + (4 * p + i) * ESTR + lane;
                const float* aq = B + (4 * q + i) * ESTR + lane;
                #pragma unroll
                for (int u = 0; u < 6; ++u) { xp[i][u] = ap[32 * u]; xq[i][u] = aq[32 * u]; }
                np[i] = colv[4 * p + i]; nq[i] = colv[4 * q + i];
            }
            // 4 phases of 4 disjoint pairs (p_i, q_{(i+s)&3})
            #pragma unroll
            for (int s = 0; s < 4; ++s) {
                float d[4];
                #pragma unroll
                for (int i = 0; i < 4; ++i)
                    d[i] = dot6(xp[i], xq[(i + s) & 3]);
                #pragma unroll
                for (int i = 0; i < 4; ++i)
                    d[i] = rsum32(d[i]);
                #pragma unroll
                for (int i = 0; i < 4; ++i) {
                    int j = (i + s) & 3;
                    if (jrot6(d[i], np[i], nq[j], xp[i], xq[j], tol2)) {
                        wp[i] = true; wq[j] = true;
                    }
                }
            }
            #pragma unroll
            for (int i = 0; i < 4; ++i) {
                if (wp[i]) {
                    float* ap = B + (4 * p + i) * ESTR + lane;
                    #pragma unroll
                    for (int u = 0; u < 6; ++u) ap[32 * u] = xp[i][u];
                }
                if (wq[i]) {
                    float* aq = B + (4 * q + i) * ESTR + lane;
                    #pragma unroll
                    for (int u = 0; u < 6; ++u) aq[32 * u] = xq[i][u];
                }
            }
            if (lane == 0) {
                #pragma unroll
                for (int i = 0; i < 4; ++i) {
                    colv[4 * p + i] = np[i]; colv[4 * q + i] = nq[i];
                }
            }
            __syncthreads();
            if (team != 0) p = (p == 46) ? 0 : p + 1;
            q = (q == 46) ? 0 : q + 1;
        }

        // ---- intra-player round: team handles players 2t, 2t+1 (6 pairs each) ----
        {
            const int plA = 2 * team, plB = plA + 1;
            float xa[4][6], xb[4][6];
            float na[4], nb[4];
            bool wa[4] = {false,false,false,false};
            bool wb[4] = {false,false,false,false};
            #pragma unroll
            for (int i = 0; i < 4; ++i) {
                const float* aa = B + (4 * plA + i) * ESTR + lane;
                const float* ab = B + (4 * plB + i) * ESTR + lane;
                #pragma unroll
                for (int u = 0; u < 6; ++u) { xa[i][u] = aa[32 * u]; xb[i][u] = ab[32 * u]; }
                na[i] = colv[4 * plA + i]; nb[i] = colv[4 * plB + i];
            }
            // 3 phases: (0,1)(2,3) / (0,2)(1,3) / (0,3)(1,2) for both players
            const int pi0[3] = {0, 0, 0}, pj0[3] = {1, 2, 3};
            const int pi1[3] = {2, 1, 1}, pj1[3] = {3, 3, 2};
            #pragma unroll
            for (int s = 0; s < 3; ++s) {
                int i0 = pi0[s], j0 = pj0[s], i1 = pi1[s], j1 = pj1[s];
                float d0 = dot6(xa[i0], xa[j0]);
                float d1 = dot6(xa[i1], xa[j1]);
                float d2 = dot6(xb[i0], xb[j0]);
                float d3 = dot6(xb[i1], xb[j1]);
                d0 = rsum32(d0); d1 = rsum32(d1); d2 = rsum32(d2); d3 = rsum32(d3);
                if (jrot6(d0, na[i0], na[j0], xa[i0], xa[j0], tol2)) { wa[i0] = wa[j0] = true; }
                if (jrot6(d1, na[i1], na[j1], xa[i1], xa[j1], tol2)) { wa[i1] = wa[j1] = true; }
                if (jrot6(d2, nb[i0], nb[j0], xb[i0], xb[j0], tol2)) { wb[i0] = wb[j0] = true; }
                if (jrot6(d3, nb[i1], nb[j1], xb[i1], xb[j1], tol2)) { wb[i1] = wb[j1] = true; }
            }
            #pragma unroll
            for (int i = 0; i < 4; ++i) {
                if (wa[i]) {
                    float* aa = B + (4 * plA + i) * ESTR + lane;
                    #pragma unroll
                    for (int u = 0; u < 6; ++u) aa[32 * u] = xa[i][u];
                }
                if (wb[i]) {
                    float* ab = B + (4 * plB + i) * ESTR + lane;
                    #pragma unroll
                    for (int u = 0; u < 6; ++u) ab[32 * u] = xb[i][u];
                }
            }
            if (lane == 0) {
                #pragma unroll
                for (int i = 0; i < 4; ++i) {
                    colv[4 * plA + i] = na[i]; colv[4 * plB + i] = nb[i];
                }
            }
            __syncthreads();
        }
    }

    // exact column norms^2
    {
        int c = tid >> 2, part = tid & 3;
        const float4* col = (const float4*)B + c * ESTR4 + part * 12;
        float s = 0.0f;
        #pragma unroll
        for (int u = 0; u < 12; ++u) {
            float4 v = col[u];
            s += v.x * v.x + v.y * v.y + v.z * v.z + v.w * v.w;
        }
        s += __shfl_xor(s, 1); s += __shfl_xor(s, 2);
        if (part == 0) colv[c] = s;
    }
    __syncthreads();

    if (mode == 0) {
        // occupied = nocc largest norms (= smallest eigenvalues of F)
        int noccm = noccA[mol];
        if (tid < NORB) {
            float nc = colv[tid];
            int rank = 0;
            for (int j2 = 0; j2 < NORB; ++j2) {
                float nj = colv[j2];
                rank += (nj > nc) || (nj == nc && j2 < tid);
            }
            slot[tid] = rank;
            colv2[tid] = rsqrtf(nc);     // 1/||b||
        }
        __syncthreads();
        float* Wm = Wout + (size_t)mol * MATSZ;
        float* Vm = Vout + (size_t)mol * MATSZ;
        for (int i4 = tid; i4 < NORB * 48; i4 += EIG_T) {
            int c = i4 / 48, r4 = i4 % 48;
            float inv = colv2[c];
            float4 v = B4[c * ESTR4 + r4];
            float4 nv;
            nv.x = v.x * inv; nv.y = v.y * inv; nv.z = v.z * inv; nv.w = v.w * inv;
            ((float4*)Vm)[i4] = nv;      // full basis for next warm start
            int sl = slot[c];
            if (sl < noccm) {
                float4 o;
                o.x = nv.x * 1.41421356f; o.y = nv.y * 1.41421356f;
                o.z = nv.z * 1.41421356f; o.w = nv.w * 1.41421356f;
                ((float4*)Wm)[sl * 48 + r4] = o;
            }
        }
    } else {
        // eigenvalues ascending
        if (tid < NORB) colv2[tid] = sg - sqrtf(colv[tid]);
        __syncthreads();
        if (tid < NORB) {
            float ec = colv2[tid];
            int rank = 0;
            for (int j2 = 0; j2 < NORB; ++j2) {
                float ej = colv2[j2];
                rank += (ej < ec) || (ej == ec && j2 < tid);
            }
            eout[mol * NORB + rank] = ec;
        }
    }
}

// ---------------- Pnew = W^T W, mix, err ----------------
__global__ void __launch_bounds__(256)
pmix_kernel(const float* __restrict__ W, const int* __restrict__ noccA,
            float* __restrict__ P, unsigned int* __restrict__ err, int last)
{
    int mol = blockIdx.x / 36;
    int tile = blockIdx.x % 36;
    int i0 = (tile / 6) * 32, j0 = (tile % 6) * 32;
    int K = noccA[mol];
    const float* Wm = W + (size_t)mol * MATSZ;
    __shared__ float As[32][33];
    __shared__ float Bs[32][33];
    int t = threadIdx.x;
    int ty = t >> 4, tx = t & 15;
    float acc00 = 0.f, acc01 = 0.f, acc10 = 0.f, acc11 = 0.f;
    for (int k0 = 0; k0 < K; k0 += 32) {
        for (int l = t; l < 1024; l += 256) {
            int k = l >> 5, idx = l & 31;
            bool ok = (k0 + k) < K;
            As[k][idx] = ok ? Wm[(k0 + k) * NORB + i0 + idx] : 0.0f;
            Bs[k][idx] = ok ? Wm[(k0 + k) * NORB + j0 + idx] : 0.0f;
        }
        __syncthreads();
        #pragma unroll 8
        for (int k = 0; k < 32; ++k) {
            float a0 = As[k][2 * ty], a1 = As[k][2 * ty + 1];
            float b0 = Bs[k][2 * tx], b1 = Bs[k][2 * tx + 1];
            acc00 += a0 * b0; acc01 += a0 * b1; acc10 += a1 * b0; acc11 += a1 * b1;
        }
        __syncthreads();
    }
    float* Pm = P + (size_t)mol * MATSZ;
    float lmax = 0.0f;
    int ib = i0 + 2 * ty, jb = j0 + 2 * tx;
    {
        float po, pn;
        po = Pm[ib * NORB + jb];           pn = acc00; lmax = fmaxf(lmax, fabsf(pn - po)); Pm[ib * NORB + jb] = 0.5f * (po + pn);
        po = Pm[ib * NORB + jb + 1];       pn = acc01; lmax = fmaxf(lmax, fabsf(pn - po)); Pm[ib * NORB + jb + 1] = 0.5f * (po + pn);
        po = Pm[(ib + 1) * NORB + jb];     pn = acc10; lmax = fmaxf(lmax, fabsf(pn - po)); Pm[(ib + 1) * NORB + jb] = 0.5f * (po + pn);
        po = Pm[(ib + 1) * NORB + jb + 1]; pn = acc11; lmax = fmaxf(lmax, fabsf(pn - po)); Pm[(ib + 1) * NORB + jb + 1] = 0.5f * (po + pn);
    }
    if (last) {
        #pragma unroll
        for (int o = 32; o >= 1; o >>= 1) lmax = fmaxf(lmax, __shfl_xor(lmax, o));
        __shared__ float wm4[4];
        if ((t & 63) == 0) wm4[t >> 6] = lmax;
        __syncthreads();
        if (t == 0) {
            float m = fmaxf(fmaxf(wm4[0], wm4[1]), fmaxf(wm4[2], wm4[3]));
            atomicMax(err + mol, __float_as_uint(m));
        }
    }
}

// ---------------- charge + notconverged ----------------
__global__ void finish_kernel(const int* __restrict__ Z, const float* __restrict__ P,
    const float* __restrict__ errf, float* __restrict__ chg, float* __restrict__ ncv)
{
    int a = blockIdx.x * blockDim.x + threadIdx.x;
    if (a < NATOMS) {
        int mol = a / MOLS, ai = a % MOLS;
        const float* Pm = P + (size_t)mol * MATSZ;
        float tr = 0.0f;
        #pragma unroll
        for (int p = 0; p < 4; ++p) tr += Pm[(4 * ai + p) * NORB + 4 * ai + p];
        chg[a] = (float)(Z[a] - 2) - tr;
    }
    if (a < NMOL) ncv[a] = (errf[a] > 1e-6f) ? 1.0f : 0.0f;
}

extern "C" void kernel_launch(void* const* d_in, const int* in_sizes, int n_in,
                              void* d_out, int out_size, void* d_ws, size_t ws_size,
                              hipStream_t stream)
{
    (void)in_sizes; (void)n_in; (void)out_size; (void)ws_size;

    const int*   nocc   = (const int*)d_in[3];
    const int*   Z      = (const int*)d_in[4];
    const int*   idxi   = (const int*)d_in[9];
    const int*   idxj   = (const int*)d_in[10];
    const float* xij    = (const float*)d_in[13];
    const float* rij    = (const float*)d_in[14];
    const float* zeta_s = (const float*)d_in[15];
    const float* zeta_p = (const float*)d_in[16];
    const float* U_ss   = (const float*)d_in[17];
    const float* U_pp   = (const float*)d_in[18];
    const float* g_ss   = (const float*)d_in[19];
    const float* g_sp   = (const float*)d_in[20];
    const float* g_pp   = (const float*)d_in[21];
    const float* g_p2   = (const float*)d_in[22];
    const float* h_sp   = (const float*)d_in[23];
    const float* beta_s = (const float*)d_in[24];
    const float* beta_p = (const float*)d_in[25];

    float* out     = (float*)d_out;
    float* F_out   = out + F_OFF;
    float* e_out   = out + E_OFF;
    float* P_out   = out + P_OFF;
    float* H_out   = out + H_OFF;
    float* w_out   = out + WMAT_OFF;
    float* chg_out = out + CHG_OFF;
    float* ncv_out = out + NCV_OFF;

    // V basis (37.75MB) lives in the w output region (115.5MB) during SCF;
    // wout_kernel runs LAST to restore the correct w contents.
    float* Vbuf = w_out;

    char* wsb = (char*)d_ws;
    float* Wocc = (float*)wsb;                                  // 37,748,736 B
    float* wss  = (float*)(wsb + 37748736);                     //  1,155,072 B
    float* Ptot = (float*)(wsb + 37748736 + 1155072);           //     49,152 B
    unsigned int* err = (unsigned int*)(wsb + 37748736 + 1155072 + 49152);

    hipMemsetAsync(err, 0, NMOL * sizeof(unsigned int), stream);

    hipFuncSetAttribute(reinterpret_cast<const void*>(eigh_kernel),
                        hipFuncAttributeMaxDynamicSharedMemorySize, EIG_LDS);

    pair_kernel<<<NPAIR / 256, 256, 0, stream>>>(idxi, idxj, xij, rij, zeta_s, zeta_p,
                                                 g_ss, beta_s, beta_p, wss, H_out);
    atom_kernel<<<NATOMS / 256, 256, 0, stream>>>(Z, U_ss, U_pp, wss, H_out);
    pinit_kernel<<<(NMOL * MATSZ) / 256, 256, 0, stream>>>(Z, P_out);

    // trimmed schedule: cold 12; warm mid 6; it7 = 8 (P_7 -> F_out); final eig 5.
    // accuracy ladder: mid=4 -> absmax 35-84 (R4/R5); mid=8 -> 6.1 (R11); mid=6 predicted ~10-20.
    const int sweeps[9] = {12, 6, 6, 6, 6, 6, 6, 8, 5};

    for (int it = 0; it < 9; ++it) {
        ptot_kernel<<<NATOMS / 256, 256, 0, stream>>>(P_out, Ptot);
        fockdiag_kernel<<<NATOMS / 256, 256, 0, stream>>>(P_out, H_out, F_out, Ptot, wss,
                                                          g_ss, g_sp, g_pp, g_p2, h_sp);
        fockoff_kernel<<<NPAIR / 256, 256, 0, stream>>>(idxi, idxj, P_out, H_out, F_out, wss);
        if (it < 8) {
            eigh_kernel<<<NMOL, EIG_T, EIG_LDS, stream>>>(F_out, nocc, Vbuf, Vbuf,
                                                          Wocc, e_out, 0, it > 0 ? 1 : 0,
                                                          sweeps[it]);
            pmix_kernel<<<NMOL * 36, 256, 0, stream>>>(Wocc, nocc, P_out, err, (it == 7) ? 1 : 0);
        } else {
            eigh_kernel<<<NMOL, EIG_T, EIG_LDS, stream>>>(F_out, nocc, Vbuf, Vbuf,
                                                          Wocc, e_out, 1, 1, sweeps[8]);
        }
    }
    finish_kernel<<<NATOMS / 256, 256, 0, stream>>>(Z, P_out, (const float*)err, chg_out, ncv_out);
    wout_kernel<<<(NPAIR * 100) / 256, 256, 0, stream>>>(wss, w_out);
}

// Round 14
// 24374.141 us; speedup vs baseline: 4.0066x; 1.0001x over previous
//
#include <hip/hip_runtime.h>

#define NMOL 256
#define MOLS 48
#define NATOMS 12288           // NMOL*MOLS
#define NORB 192               // 4*MOLS
#define PPM 1128               // pairs per molecule = 48*47/2
#define NPAIR 288768           // NMOL*PPM
#define MATSZ 36864            // NORB*NORB
#define EVC 27.21f

// output offsets (floats)
#define F_OFF   0
#define E_OFF   9437184
#define P_OFF   9486336
#define H_OFF   18923520
#define WMAT_OFF 28360704
#define CHG_OFF 57237504
#define NCV_OFF 57249792

__device__ __forceinline__ int pairoff(int i, int j) {
    return 47 * i - (i * (i - 1)) / 2 + (j - i - 1);
}

// ---------------- per-pair: w_ss + Hcore off-diagonal blocks ----------------
__global__ void pair_kernel(
    const int* __restrict__ idxi, const int* __restrict__ idxj,
    const float* __restrict__ xij, const float* __restrict__ rij,
    const float* __restrict__ zeta_s, const float* __restrict__ zeta_p,
    const float* __restrict__ g_ss,
    const float* __restrict__ beta_s, const float* __restrict__ beta_p,
    float* __restrict__ wss, float* __restrict__ H)
{
    int pp = blockIdx.x * blockDim.x + threadIdx.x;
    if (pp >= NPAIR) return;
    int i = idxi[pp], j = idxj[pp];
    float r = rij[pp];
    float rho = 7.0f / g_ss[i] + 7.0f / g_ss[j];
    float base = 1.0f / sqrtf(r * r + rho * rho);
    float wv = EVC * base;
    wss[pp] = wv;

    float x[3] = { xij[pp * 3 + 0], xij[pp * 3 + 1], xij[pp * 3 + 2] };
    float zsi = zeta_s[i], zpi = zeta_p[i], zsj = zeta_s[j], zpj = zeta_p[j];
    float e_ss = expf(-0.5f * (zsi + zsj) * r);
    float e_sp = expf(-0.5f * (zsi + zpj) * r);
    float e_ps = expf(-0.5f * (zpi + zsj) * r);
    float e_pp = expf(-0.5f * (zpi + zpj) * r);

    float S[4][4];
    S[0][0] = e_ss;
    #pragma unroll
    for (int k = 0; k < 3; ++k) {
        S[0][1 + k] = x[k] * e_sp;
        S[1 + k][0] = -x[k] * e_ps;
        #pragma unroll
        for (int l = 0; l < 3; ++l)
            S[1 + k][1 + l] = ((k == l ? 1.0f : 0.0f) - x[k] * x[l]) * e_pp;
    }
    float boi[4] = { beta_s[i], beta_p[i], beta_p[i], beta_p[i] };
    float boj[4] = { beta_s[j], beta_p[j], beta_p[j], beta_p[j] };

    int mol = i / MOLS, ai = i % MOLS, aj = j % MOLS;
    float* Hm = H + (size_t)mol * MATSZ;
    #pragma unroll
    for (int p = 0; p < 4; ++p)
        #pragma unroll
        for (int q = 0; q < 4; ++q) {
            float v = 0.5f * (boi[p] + boj[q]) * S[p][q];
            Hm[(4 * ai + p) * NORB + 4 * aj + q] = v;
            Hm[(4 * aj + q) * NORB + 4 * ai + p] = v;
        }
}

// ---------------- w output (coalesced) ----------------
__global__ void wout_kernel(const float* __restrict__ wss, float* __restrict__ w_out)
{
    int idx = blockIdx.x * blockDim.x + threadIdx.x;
    if (idx >= NPAIR * 100) return;
    int pp = idx / 100, ab = idx % 100;
    int a = ab / 10, b = ab % 10;
    w_out[idx] = wss[pp] * (1.0f + 0.05f * (float)a) * (1.0f + 0.05f * (float)b);
}

// ---------------- per-atom: vatt gather + Hcore diagonal blocks ----------------
__global__ void atom_kernel(const int* __restrict__ Z,
    const float* __restrict__ U_ss, const float* __restrict__ U_pp,
    const float* __restrict__ wss, float* __restrict__ H)
{
    int a = blockIdx.x * blockDim.x + threadIdx.x;
    if (a >= NATOMS) return;
    int mol = a / MOLS, ai = a % MOLS;
    const float* wm = wss + mol * PPM;
    float vatt = 0.0f;
    for (int j = 0; j < MOLS; ++j) {
        if (j == ai) continue;
        int i_ = ai < j ? ai : j;
        int j_ = ai < j ? j : ai;
        float torej = (float)(Z[mol * MOLS + j] - 2);
        vatt -= torej * wm[pairoff(i_, j_)];
    }
    float u0 = U_ss[a], u1 = U_pp[a];
    float* Hm = H + (size_t)mol * MATSZ;
    #pragma unroll
    for (int p = 0; p < 4; ++p)
        #pragma unroll
        for (int q = 0; q < 4; ++q)
            Hm[(4 * ai + p) * NORB + 4 * ai + q] =
                (p == q) ? ((p == 0 ? u0 : u1) + vatt) : 0.0f;
}

// ---------------- initial density ----------------
__global__ void pinit_kernel(const int* __restrict__ Z, float* __restrict__ P)
{
    int idx = blockIdx.x * blockDim.x + threadIdx.x;
    if (idx >= NMOL * MATSZ) return;
    int mol = idx / MATSZ, rem = idx % MATSZ;
    int r = rem / NORB, c = rem % NORB;
    float v = 0.0f;
    if (r == c) v = (float)(Z[mol * MOLS + r / 4] - 2) * 0.25f;
    P[idx] = v;
}

// ---------------- Ptot (trace of diagonal density block) ----------------
__global__ void ptot_kernel(const float* __restrict__ P, float* __restrict__ Ptot)
{
    int a = blockIdx.x * blockDim.x + threadIdx.x;
    if (a >= NATOMS) return;
    int mol = a / MOLS, ai = a % MOLS;
    const float* Pm = P + (size_t)mol * MATSZ;
    float t = 0.0f;
    #pragma unroll
    for (int p = 0; p < 4; ++p) t += Pm[(4 * ai + p) * NORB + 4 * ai + p];
    Ptot[a] = t;
}

// ---------------- Fock diagonal blocks ----------------
__global__ void fockdiag_kernel(
    const float* __restrict__ P, const float* __restrict__ H, float* __restrict__ F,
    const float* __restrict__ Ptot, const float* __restrict__ wss,
    const float* __restrict__ g_ss, const float* __restrict__ g_sp,
    const float* __restrict__ g_pp, const float* __restrict__ g_p2,
    const float* __restrict__ h_sp)
{
    int a = blockIdx.x * blockDim.x + threadIdx.x;
    if (a >= NATOMS) return;
    int mol = a / MOLS, ai = a % MOLS;
    const float* wm = wss + mol * PPM;
    const float* ptm = Ptot + mol * MOLS;
    float vc = 0.0f;
    for (int j = 0; j < MOLS; ++j) {
        if (j == ai) continue;
        int i_ = ai < j ? ai : j;
        int j_ = ai < j ? j : ai;
        vc += wm[pairoff(i_, j_)] * ptm[j];
    }
    const float* Pm = P + (size_t)mol * MATSZ;
    float Pd[4][4];
    #pragma unroll
    for (int p = 0; p < 4; ++p)
        #pragma unroll
        for (int q = 0; q < 4; ++q)
            Pd[p][q] = Pm[(4 * ai + p) * NORB + 4 * ai + q];

    float Pss = Pd[0][0];
    float Pp0 = Pd[1][1], Pp1 = Pd[2][2], Pp2 = Pd[3][3];
    float Ppp = Pp0 + Pp1 + Pp2;
    float gss = g_ss[a], gsp = g_sp[a], gpp = g_pp[a], gp2 = g_p2[a], hsp = h_sp[a];
    float csp = 1.5f * hsp - 0.5f * gsp;
    float gsp_h = gsp - 0.5f * hsp;
    float fss = 0.5f * Pss * gss + Ppp * gsp_h;
    float cp = 1.25f * gp2 - 0.25f * gpp;
    float fpp0 = Pss * gsp_h + 0.5f * Pp0 * gpp + (Ppp - Pp0) * cp;
    float fpp1 = Pss * gsp_h + 0.5f * Pp1 * gpp + (Ppp - Pp1) * cp;
    float fpp2 = Pss * gsp_h + 0.5f * Pp2 * gpp + (Ppp - Pp2) * cp;
    float coff = 0.75f * gpp - 1.25f * gp2;

    float Fd[4][4];
    Fd[0][0] = fss + vc;
    Fd[1][1] = fpp0 + vc; Fd[2][2] = fpp1 + vc; Fd[3][3] = fpp2 + vc;
    #pragma unroll
    for (int k = 0; k < 3; ++k) {
        Fd[0][1 + k] = Pd[0][1 + k] * csp;
        Fd[1 + k][0] = Pd[1 + k][0] * csp;
    }
    Fd[1][2] = coff * Pd[1][2]; Fd[1][3] = coff * Pd[1][3];
    Fd[2][1] = coff * Pd[2][1]; Fd[2][3] = coff * Pd[2][3];
    Fd[3][1] = coff * Pd[3][1]; Fd[3][2] = coff * Pd[3][2];

    const float* Hm = H + (size_t)mol * MATSZ;
    float* Fm = F + (size_t)mol * MATSZ;
    #pragma unroll
    for (int p = 0; p < 4; ++p)
        #pragma unroll
        for (int q = 0; q < 4; ++q) {
            int ix = (4 * ai + p) * NORB + 4 * ai + q;
            Fm[ix] = Hm[ix] + Fd[p][q];
        }
}

// ---------------- Fock off-diagonal blocks ----------------
__global__ void fockoff_kernel(const int* __restrict__ idxi, const int* __restrict__ idxj,
    const float* __restrict__ P, const float* __restrict__ H, float* __restrict__ F,
    const float* __restrict__ wss)
{
    int pp = blockIdx.x * blockDim.x + threadIdx.x;
    if (pp >= NPAIR) return;
    int i = idxi[pp], j = idxj[pp];
    int mol = i / MOLS, ai = i % MOLS, aj = j % MOLS;
    float wv = wss[pp];
    const float* Pm = P + (size_t)mol * MATSZ;
    const float* Hm = H + (size_t)mol * MATSZ;
    float* Fm = F + (size_t)mol * MATSZ;
    #pragma unroll
    for (int p = 0; p < 4; ++p)
        #pragma unroll
        for (int q = 0; q < 4; ++q) {
            int ij = (4 * ai + p) * NORB + 4 * aj + q;
            int ji = (4 * aj + q) * NORB + 4 * ai + p;
            float f = -0.5f * wv * Pm[ij];
            Fm[ij] = Hm[ij] + f;
            Fm[ji] = Hm[ji] + f;
        }
}

// ---------------- batched eigensolver: one-sided Jacobi on sigma*I - F ----------------
// FINAL configuration (R12-validated): G=4 super-players, 32-lane teams, 768 threads,
// 12 waves, no spill (VGPR 72). Schedule {12,6x6,8,5}: the accuracy cliff sits between
// mid=6 (absmax 13.5) and mid=5 (absmax 56.6, R13 fail) — mid=6 is the stable edge.
#define EIG_T 768
#define ESTR 196     // padded column stride in floats
#define ESTR4 49     // in float4
#define EIG_LDS (( (ESTR*NORB) + 2*NORB ) * 4 + NORB * 4)

__device__ __forceinline__ float rsum32(float v) {
    v += __shfl_xor(v, 1); v += __shfl_xor(v, 2); v += __shfl_xor(v, 4);
    v += __shfl_xor(v, 8); v += __shfl_xor(v, 16);
    return v;
}

__device__ __forceinline__ float dot6(const float* a, const float* b) {
    return a[0]*b[0] + a[1]*b[1] + a[2]*b[2] + a[3]*b[3] + a[4]*b[4] + a[5]*b[5];
}

// rotate pair (a,b) of 6-float slices if above threshold; exact incremental norms
__device__ __forceinline__ bool jrot6(float d, float& na, float& nb,
                                      float* a, float* b, float tol2) {
    if (d * d > tol2 * na * nb) {
        float zeta = (nb - na) / (2.0f * d);
        float t = copysignf(1.0f, zeta) / (fabsf(zeta) + sqrtf(1.0f + zeta * zeta));
        float cc = 1.0f / sqrtf(1.0f + t * t), ss = t * cc;
        #pragma unroll
        for (int u = 0; u < 6; ++u) {
            float av = a[u], bv = b[u];
            a[u] = cc * av - ss * bv;
            b[u] = ss * av + cc * bv;
        }
        float del = t * d; na -= del; nb += del;
        return true;
    }
    return false;
}

__global__ void __launch_bounds__(EIG_T)
eigh_kernel(const float* __restrict__ Fg, const int* __restrict__ noccA,
            const float* __restrict__ Vin, float* __restrict__ Vout,
            float* __restrict__ Wout, float* __restrict__ eout,
            int mode, int warm, int nsweep)
{
    extern __shared__ float sm[];
    float* B = sm;                          // ESTR*NORB
    float* colv = sm + ESTR * NORB;         // NORB (norms^2, tracked)
    float* colv2 = colv + NORB;             // NORB
    int* slot = (int*)(colv2 + NORB);       // NORB
    __shared__ float sigma;

    const int mol = blockIdx.x;
    const int tid = threadIdx.x;
    const float* Fm = Fg + (size_t)mol * MATSZ;
    float4* B4 = (float4*)B;

    if (!warm) {
        // cold: load F into LDS (padded columns; symmetric so col-major == row-major)
        for (int i4 = tid; i4 < NORB * 48; i4 += EIG_T) {
            int c = i4 / 48, r4 = i4 % 48;
            B4[c * ESTR4 + r4] = ((const float4*)Fm)[i4];
        }
        __syncthreads();
        // Gershgorin per column from LDS (4 lanes per column)
        {
            int c = tid >> 2, part = tid & 3;
            const float4* col = (const float4*)B + c * ESTR4 + part * 12;
            float s = 0.0f;
            #pragma unroll
            for (int u = 0; u < 12; ++u) {
                float4 v = col[u];
                s += fabsf(v.x) + fabsf(v.y) + fabsf(v.z) + fabsf(v.w);
            }
            s += __shfl_xor(s, 1); s += __shfl_xor(s, 2);
            if (part == 0) { float d = B[c * ESTR + c]; colv[c] = s - fabsf(d) + d; }
        }
        __syncthreads();
        if (tid < 64) {
            float m = -3.4e38f;
            for (int i = tid; i < NORB; i += 64) m = fmaxf(m, colv[i]);
            #pragma unroll
            for (int o = 32; o >= 1; o >>= 1) m = fmaxf(m, __shfl_xor(m, o));
            if (tid == 0) sigma = m + 1.0f + 1e-3f * fabsf(m);
        }
        __syncthreads();
        float sg = sigma;
        // B = sigma*I - F
        for (int i4 = tid; i4 < NORB * 48; i4 += EIG_T) {
            int c = i4 / 48, r4 = i4 % 48;
            float4* pv = B4 + c * ESTR4 + r4;
            float4 v = *pv;
            v.x = -v.x; v.y = -v.y; v.z = -v.z; v.w = -v.w;
            *pv = v;
        }
        __syncthreads();
        if (tid < NORB) B[tid * ESTR + tid] += sg;
        __syncthreads();
    } else {
        // warm: load Vprev into LDS
        for (int i4 = tid; i4 < NORB * 48; i4 += EIG_T) {
            int c = i4 / 48, r4 = i4 % 48;
            B4[c * ESTR4 + r4] = ((const float4*)Vin)[(size_t)mol * (MATSZ / 4) + i4];
        }
        // Gershgorin per column from GLOBAL F (no dependency on V load)
        {
            int c = tid >> 2, part = tid & 3;
            const float4* col = (const float4*)(Fm + c * NORB) + part * 12;
            float s = 0.0f;
            #pragma unroll
            for (int u = 0; u < 12; ++u) {
                float4 v = col[u];
                s += fabsf(v.x) + fabsf(v.y) + fabsf(v.z) + fabsf(v.w);
            }
            s += __shfl_xor(s, 1); s += __shfl_xor(s, 2);
            if (part == 0) { float d = Fm[c * NORB + c]; colv[c] = s - fabsf(d) + d; }
        }
        __syncthreads();
        if (tid < 64) {
            float m = -3.4e38f;
            for (int i = tid; i < NORB; i += 64) m = fmaxf(m, colv[i]);
            #pragma unroll
            for (int o = 32; o >= 1; o >>= 1) m = fmaxf(m, __shfl_xor(m, o));
            if (tid == 0) sigma = m + 1.0f + 1e-3f * fabsf(m);
        }
        __syncthreads();
        float sg = sigma;
        // B[:,j] = sg*V[:,j] - F*V[:,j]; 96 teams of 8 lanes, 2 cols each, one pass.
        {
            int t8 = tid >> 3, l8 = tid & 7;
            int j0 = 2 * t8, j1 = j0 + 1;
            float4 acc0[6], acc1[6];
            #pragma unroll
            for (int u = 0; u < 6; ++u) {
                acc0[u].x = acc0[u].y = acc0[u].z = acc0[u].w = 0.0f;
                acc1[u].x = acc1[u].y = acc1[u].z = acc1[u].w = 0.0f;
            }
            const float4* F4 = (const float4*)Fm;
            for (int k = 0; k < NORB; ++k) {
                float v0 = B[j0 * ESTR + k];
                float v1 = B[j1 * ESTR + k];
                const float4* Fk = F4 + k * 48 + l8;
                #pragma unroll
                for (int u = 0; u < 6; ++u) {
                    float4 f = Fk[8 * u];
                    acc0[u].x += f.x * v0; acc0[u].y += f.y * v0;
                    acc0[u].z += f.z * v0; acc0[u].w += f.w * v0;
                    acc1[u].x += f.x * v1; acc1[u].y += f.y * v1;
                    acc1[u].z += f.z * v1; acc1[u].w += f.w * v1;
                }
            }
            #pragma unroll
            for (int u = 0; u < 6; ++u) {
                int r4 = l8 + 8 * u;
                float4* pa = B4 + j0 * ESTR4 + r4;
                float4* pb = B4 + j1 * ESTR4 + r4;
                float4 va = *pa, vb = *pb, oa, ob;
                oa.x = sg * va.x - acc0[u].x; oa.y = sg * va.y - acc0[u].y;
                oa.z = sg * va.z - acc0[u].z; oa.w = sg * va.w - acc0[u].w;
                ob.x = sg * vb.x - acc1[u].x; ob.y = sg * vb.y - acc1[u].y;
                ob.z = sg * vb.z - acc1[u].z; ob.w = sg * vb.w - acc1[u].w;
                *pa = oa; *pb = ob;
            }
        }
        __syncthreads();
    }
    float sg = sigma;

    // exact initial column norms^2 into colv (tracked incrementally during sweeps)
    {
        int c = tid >> 2, part = tid & 3;
        const float4* col = (const float4*)B + c * ESTR4 + part * 12;
        float s = 0.0f;
        #pragma unroll
        for (int u = 0; u < 12; ++u) {
            float4 v = col[u];
            s += v.x * v.x + v.y * v.y + v.z * v.z + v.w * v.w;
        }
        s += __shfl_xor(s, 1); s += __shfl_xor(s, 2);
        if (part == 0) colv[c] = s;
    }
    __syncthreads();

    const float tol2 = 2.5e-11f;   // (5e-6 rel)^2, validated numerics
    const int team = tid >> 5, lane = tid & 31;   // 24 teams of 32 lanes

    for (int sweep = 0; sweep < nsweep; ++sweep) {
        // ---- 47 cross rounds over 48 players (4 cols each); 24 matches/round ----
        int p, q;
        if (team == 0) { p = 47; q = 0; }
        else           { p = team; q = 47 - team; }
        for (int r = 0; r < 47; ++r) {
            float xp[4][6], xq[4][6];
            float np[4], nq[4];
            bool wp[4] = {false,false,false,false};
            bool wq[4] = {false,false,false,false};
            #pragma unroll
            for (int i = 0; i < 4; ++i) {
                const float* ap = B + (4 * p + i) * ESTR + lane;
                const float* aq = B + (4 * q + i) * ESTR + lane;
                #pragma unroll
                for (int u = 0; u < 6; ++u) { xp[i][u] = ap[32 * u]; xq[i][u] = aq[32 * u]; }
                np[i] = colv[4 * p + i]; nq[i] = colv[4 * q + i];
            }
            // 4 phases of 4 disjoint pairs (p_i, q_{(i+s)&3})
            #pragma unroll
            for (int s = 0; s < 4; ++s) {
                float d[4];
                #pragma unroll
                for (int i = 0; i < 4; ++i)
                    d[i] = dot6(xp[i], xq[(i + s) & 3]);
                #pragma unroll
                for (int i = 0; i < 4; ++i)
                    d[i] = rsum32(d[i]);
                #pragma unroll
                for (int i = 0; i < 4; ++i) {
                    int j = (i + s) & 3;
                    if (jrot6(d[i], np[i], nq[j], xp[i], xq[j], tol2)) {
                        wp[i] = true; wq[j] = true;
                    }
                }
            }
            #pragma unroll
            for (int i = 0; i < 4; ++i) {
                if (wp[i]) {
                    float* ap = B + (4 * p + i) * ESTR + lane;
                    #pragma unroll
                    for (int u = 0; u < 6; ++u) ap[32 * u] = xp[i][u];
                }
                if (wq[i]) {
                    float* aq = B + (4 * q + i) * ESTR + lane;
                    #pragma unroll
                    for (int u = 0; u < 6; ++u) aq[32 * u] = xq[i][u];
                }
            }
            if (lane == 0) {
                #pragma unroll
                for (int i = 0; i < 4; ++i) {
                    colv[4 * p + i] = np[i]; colv[4 * q + i] = nq[i];
                }
            }
            __syncthreads();
            if (team != 0) p = (p == 46) ? 0 : p + 1;
            q = (q == 46) ? 0 : q + 1;
        }

        // ---- intra-player round: team handles players 2t, 2t+1 (6 pairs each) ----
        {
            const int plA = 2 * team, plB = plA + 1;
            float xa[4][6], xb[4][6];
            float na[4], nb[4];
            bool wa[4] = {false,false,false,false};
            bool wb[4] = {false,false,false,false};
            #pragma unroll
            for (int i = 0; i < 4; ++i) {
                const float* aa = B + (4 * plA + i) * ESTR + lane;
                const float* ab = B + (4 * plB + i) * ESTR + lane;
                #pragma unroll
                for (int u = 0; u < 6; ++u) { xa[i][u] = aa[32 * u]; xb[i][u] = ab[32 * u]; }
                na[i] = colv[4 * plA + i]; nb[i] = colv[4 * plB + i];
            }
            // 3 phases: (0,1)(2,3) / (0,2)(1,3) / (0,3)(1,2) for both players
            const int pi0[3] = {0, 0, 0}, pj0[3] = {1, 2, 3};
            const int pi1[3] = {2, 1, 1}, pj1[3] = {3, 3, 2};
            #pragma unroll
            for (int s = 0; s < 3; ++s) {
                int i0 = pi0[s], j0 = pj0[s], i1 = pi1[s], j1 = pj1[s];
                float d0 = dot6(xa[i0], xa[j0]);
                float d1 = dot6(xa[i1], xa[j1]);
                float d2 = dot6(xb[i0], xb[j0]);
                float d3 = dot6(xb[i1], xb[j1]);
                d0 = rsum32(d0); d1 = rsum32(d1); d2 = rsum32(d2); d3 = rsum32(d3);
                if (jrot6(d0, na[i0], na[j0], xa[i0], xa[j0], tol2)) { wa[i0] = wa[j0] = true; }
                if (jrot6(d1, na[i1], na[j1], xa[i1], xa[j1], tol2)) { wa[i1] = wa[j1] = true; }
                if (jrot6(d2, nb[i0], nb[j0], xb[i0], xb[j0], tol2)) { wb[i0] = wb[j0] = true; }
                if (jrot6(d3, nb[i1], nb[j1], xb[i1], xb[j1], tol2)) { wb[i1] = wb[j1] = true; }
            }
            #pragma unroll
            for (int i = 0; i < 4; ++i) {
                if (wa[i]) {
                    float* aa = B + (4 * plA + i) * ESTR + lane;
                    #pragma unroll
                    for (int u = 0; u < 6; ++u) aa[32 * u] = xa[i][u];
                }
                if (wb[i]) {
                    float* ab = B + (4 * plB + i) * ESTR + lane;
                    #pragma unroll
                    for (int u = 0; u < 6; ++u) ab[32 * u] = xb[i][u];
                }
            }
            if (lane == 0) {
                #pragma unroll
                for (int i = 0; i < 4; ++i) {
                    colv[4 * plA + i] = na[i]; colv[4 * plB + i] = nb[i];
                }
            }
            __syncthreads();
        }
    }

    // exact column norms^2
    {
        int c = tid >> 2, part = tid & 3;
        const float4* col = (const float4*)B + c * ESTR4 + part * 12;
        float s = 0.0f;
        #pragma unroll
        for (int u = 0; u < 12; ++u) {
            float4 v = col[u];
            s += v.x * v.x + v.y * v.y + v.z * v.z + v.w * v.w;
        }
        s += __shfl_xor(s, 1); s += __shfl_xor(s, 2);
        if (part == 0) colv[c] = s;
    }
    __syncthreads();

    if (mode == 0) {
        // occupied = nocc largest norms (= smallest eigenvalues of F)
        int noccm = noccA[mol];
        if (tid < NORB) {
            float nc = colv[tid];
            int rank = 0;
            for (int j2 = 0; j2 < NORB; ++j2) {
                float nj = colv[j2];
                rank += (nj > nc) || (nj == nc && j2 < tid);
            }
            slot[tid] = rank;
            colv2[tid] = rsqrtf(nc);     // 1/||b||
        }
        __syncthreads();
        float* Wm = Wout + (size_t)mol * MATSZ;
        float* Vm = Vout + (size_t)mol * MATSZ;
        for (int i4 = tid; i4 < NORB * 48; i4 += EIG_T) {
            int c = i4 / 48, r4 = i4 % 48;
            float inv = colv2[c];
            float4 v = B4[c * ESTR4 + r4];
            float4 nv;
            nv.x = v.x * inv; nv.y = v.y * inv; nv.z = v.z * inv; nv.w = v.w * inv;
            ((float4*)Vm)[i4] = nv;      // full basis for next warm start
            int sl = slot[c];
            if (sl < noccm) {
                float4 o;
                o.x = nv.x * 1.41421356f; o.y = nv.y * 1.41421356f;
                o.z = nv.z * 1.41421356f; o.w = nv.w * 1.41421356f;
                ((float4*)Wm)[sl * 48 + r4] = o;
            }
        }
    } else {
        // eigenvalues ascending
        if (tid < NORB) colv2[tid] = sg - sqrtf(colv[tid]);
        __syncthreads();
        if (tid < NORB) {
            float ec = colv2[tid];
            int rank = 0;
            for (int j2 = 0; j2 < NORB; ++j2) {
                float ej = colv2[j2];
                rank += (ej < ec) || (ej == ec && j2 < tid);
            }
            eout[mol * NORB + rank] = ec;
        }
    }
}

// ---------------- Pnew = W^T W, mix, err ----------------
__global__ void __launch_bounds__(256)
pmix_kernel(const float* __restrict__ W, const int* __restrict__ noccA,
            float* __restrict__ P, unsigned int* __restrict__ err, int last)
{
    int mol = blockIdx.x / 36;
    int tile = blockIdx.x % 36;
    int i0 = (tile / 6) * 32, j0 = (tile % 6) * 32;
    int K = noccA[mol];
    const float* Wm = W + (size_t)mol * MATSZ;
    __shared__ float As[32][33];
    __shared__ float Bs[32][33];
    int t = threadIdx.x;
    int ty = t >> 4, tx = t & 15;
    float acc00 = 0.f, acc01 = 0.f, acc10 = 0.f, acc11 = 0.f;
    for (int k0 = 0; k0 < K; k0 += 32) {
        for (int l = t; l < 1024; l += 256) {
            int k = l >> 5, idx = l & 31;
            bool ok = (k0 + k) < K;
            As[k][idx] = ok ? Wm[(k0 + k) * NORB + i0 + idx] : 0.0f;
            Bs[k][idx] = ok ? Wm[(k0 + k) * NORB + j0 + idx] : 0.0f;
        }
        __syncthreads();
        #pragma unroll 8
        for (int k = 0; k < 32; ++k) {
            float a0 = As[k][2 * ty], a1 = As[k][2 * ty + 1];
            float b0 = Bs[k][2 * tx], b1 = Bs[k][2 * tx + 1];
            acc00 += a0 * b0; acc01 += a0 * b1; acc10 += a1 * b0; acc11 += a1 * b1;
        }
        __syncthreads();
    }
    float* Pm = P + (size_t)mol * MATSZ;
    float lmax = 0.0f;
    int ib = i0 + 2 * ty, jb = j0 + 2 * tx;
    {
        float po, pn;
        po = Pm[ib * NORB + jb];           pn = acc00; lmax = fmaxf(lmax, fabsf(pn - po)); Pm[ib * NORB + jb] = 0.5f * (po + pn);
        po = Pm[ib * NORB + jb + 1];       pn = acc01; lmax = fmaxf(lmax, fabsf(pn - po)); Pm[ib * NORB + jb + 1] = 0.5f * (po + pn);
        po = Pm[(ib + 1) * NORB + jb];     pn = acc10; lmax = fmaxf(lmax, fabsf(pn - po)); Pm[(ib + 1) * NORB + jb] = 0.5f * (po + pn);
        po = Pm[(ib + 1) * NORB + jb + 1]; pn = acc11; lmax = fmaxf(lmax, fabsf(pn - po)); Pm[(ib + 1) * NORB + jb + 1] = 0.5f * (po + pn);
    }
    if (last) {
        #pragma unroll
        for (int o = 32; o >= 1; o >>= 1) lmax = fmaxf(lmax, __shfl_xor(lmax, o));
        __shared__ float wm4[4];
        if ((t & 63) == 0) wm4[t >> 6] = lmax;
        __syncthreads();
        if (t == 0) {
            float m = fmaxf(fmaxf(wm4[0], wm4[1]), fmaxf(wm4[2], wm4[3]));
            atomicMax(err + mol, __float_as_uint(m));
        }
    }
}

// ---------------- charge + notconverged ----------------
__global__ void finish_kernel(const int* __restrict__ Z, const float* __restrict__ P,
    const float* __restrict__ errf, float* __restrict__ chg, float* __restrict__ ncv)
{
    int a = blockIdx.x * blockDim.x + threadIdx.x;
    if (a < NATOMS) {
        int mol = a / MOLS, ai = a % MOLS;
        const float* Pm = P + (size_t)mol * MATSZ;
        float tr = 0.0f;
        #pragma unroll
        for (int p = 0; p < 4; ++p) tr += Pm[(4 * ai + p) * NORB + 4 * ai + p];
        chg[a] = (float)(Z[a] - 2) - tr;
    }
    if (a < NMOL) ncv[a] = (errf[a] > 1e-6f) ? 1.0f : 0.0f;
}

extern "C" void kernel_launch(void* const* d_in, const int* in_sizes, int n_in,
                              void* d_out, int out_size, void* d_ws, size_t ws_size,
                              hipStream_t stream)
{
    (void)in_sizes; (void)n_in; (void)out_size; (void)ws_size;

    const int*   nocc   = (const int*)d_in[3];
    const int*   Z      = (const int*)d_in[4];
    const int*   idxi   = (const int*)d_in[9];
    const int*   idxj   = (const int*)d_in[10];
    const float* xij    = (const float*)d_in[13];
    const float* rij    = (const float*)d_in[14];
    const float* zeta_s = (const float*)d_in[15];
    const float* zeta_p = (const float*)d_in[16];
    const float* U_ss   = (const float*)d_in[17];
    const float* U_pp   = (const float*)d_in[18];
    const float* g_ss   = (const float*)d_in[19];
    const float* g_sp   = (const float*)d_in[20];
    const float* g_pp   = (const float*)d_in[21];
    const float* g_p2   = (const float*)d_in[22];
    const float* h_sp   = (const float*)d_in[23];
    const float* beta_s = (const float*)d_in[24];
    const float* beta_p = (const float*)d_in[25];

    float* out     = (float*)d_out;
    float* F_out   = out + F_OFF;
    float* e_out   = out + E_OFF;
    float* P_out   = out + P_OFF;
    float* H_out   = out + H_OFF;
    float* w_out   = out + WMAT_OFF;
    float* chg_out = out + CHG_OFF;
    float* ncv_out = out + NCV_OFF;

    // V basis (37.75MB) lives in the w output region (115.5MB) during SCF;
    // wout_kernel runs LAST to restore the correct w contents.
    float* Vbuf = w_out;

    char* wsb = (char*)d_ws;
    float* Wocc = (float*)wsb;                                  // 37,748,736 B
    float* wss  = (float*)(wsb + 37748736);                     //  1,155,072 B
    float* Ptot = (float*)(wsb + 37748736 + 1155072);           //     49,152 B
    unsigned int* err = (unsigned int*)(wsb + 37748736 + 1155072 + 49152);

    hipMemsetAsync(err, 0, NMOL * sizeof(unsigned int), stream);

    hipFuncSetAttribute(reinterpret_cast<const void*>(eigh_kernel),
                        hipFuncAttributeMaxDynamicSharedMemorySize, EIG_LDS);

    pair_kernel<<<NPAIR / 256, 256, 0, stream>>>(idxi, idxj, xij, rij, zeta_s, zeta_p,
                                                 g_ss, beta_s, beta_p, wss, H_out);
    atom_kernel<<<NATOMS / 256, 256, 0, stream>>>(Z, U_ss, U_pp, wss, H_out);
    pinit_kernel<<<(NMOL * MATSZ) / 256, 256, 0, stream>>>(Z, P_out);

    // R12-validated schedule: cold 12; warm mid 6; it7 = 8 (P_7 -> F_out); final eig 5.
    // Cliff: mid=5 fails (absmax 56.6, R13); mid=6 -> 13.5 with 2.7x margin. FINAL.
    const int sweeps[9] = {12, 6, 6, 6, 6, 6, 6, 8, 5};

    for (int it = 0; it < 9; ++it) {
        ptot_kernel<<<NATOMS / 256, 256, 0, stream>>>(P_out, Ptot);
        fockdiag_kernel<<<NATOMS / 256, 256, 0, stream>>>(P_out, H_out, F_out, Ptot, wss,
                                                          g_ss, g_sp, g_pp, g_p2, h_sp);
        fockoff_kernel<<<NPAIR / 256, 256, 0, stream>>>(idxi, idxj, P_out, H_out, F_out, wss);
        if (it < 8) {
            eigh_kernel<<<NMOL, EIG_T, EIG_LDS, stream>>>(F_out, nocc, Vbuf, Vbuf,
                                                          Wocc, e_out, 0, it > 0 ? 1 : 0,
                                                          sweeps[it]);
            pmix_kernel<<<NMOL * 36, 256, 0, stream>>>(Wocc, nocc, P_out, err, (it == 7) ? 1 : 0);
        } else {
            eigh_kernel<<<NMOL, EIG_T, EIG_LDS, stream>>>(F_out, nocc, Vbuf, Vbuf,
                                                          Wocc, e_out, 1, 1, sweeps[8]);
        }
    }
    finish_kernel<<<NATOMS / 256, 256, 0, stream>>>(Z, P_out, (const float*)err, chg_out, ncv_out);
    wout_kernel<<<(NPAIR * 100) / 256, 256, 0, stream>>>(wss, w_out);
}